// Round 12
// baseline (316.886 us; speedup 1.0000x reference)
//
#include <hip/hip_runtime.h>
#include <math.h>

#define NB    16
#define CIx   256
#define COx   128
#define NPTS  2000
#define KW    9
#define NKx   18000   // NPTS*KW
#define NTIL  25      // n tiles of 80 for mconv
#define PSTRIDE 51200 // NB*NTIL*128

typedef short bf16x8 __attribute__((ext_vector_type(8)));
typedef float f32x4  __attribute__((ext_vector_type(4)));
typedef unsigned short us4 __attribute__((ext_vector_type(4)));
typedef unsigned short us8 __attribute__((ext_vector_type(8)));

__device__ __forceinline__ ushort f2bf(float f){
  unsigned u = __builtin_bit_cast(unsigned, f);
  u = (u + 0x7fffu + ((u>>16)&1u)) >> 16;
  return (ushort)u;
}
__device__ __forceinline__ float bf2f(ushort h){
  unsigned u = ((unsigned)h)<<16;
  return __builtin_bit_cast(float, u);
}
// per-mt within-slot placement permutation: bijective, puts mt parity into bank bit 4
__device__ __forceinline__ int pi16(int c, int mt){
  return (((c & 3) ^ (mt & 3)) << 2) | (c >> 2);
}

// ---------------- stats over x_local + free raw bf16 copy ----------------
__global__ __launch_bounds__(256) void k_xstats(const float* __restrict__ xl,
    float* __restrict__ sum, float* __restrict__ sumsq, ushort* __restrict__ xlb){
  int bi = blockIdx.x;                       // b*256 + i
  const float4* p = (const float4*)(xl + (size_t)bi * NKx);
  ushort* ob = xlb + (size_t)bi * NKx;
  float s = 0.f, ss = 0.f;
  for (int idx = threadIdx.x; idx < NKx/4; idx += 256){
    float4 v = p[idx];
    s  += v.x + v.y + v.z + v.w;
    ss += v.x*v.x + v.y*v.y + v.z*v.z + v.w*v.w;
    us4 pk;
    pk[0] = f2bf(v.x); pk[1] = f2bf(v.y); pk[2] = f2bf(v.z); pk[3] = f2bf(v.w);
    *(us4*)(ob + idx*4) = pk;
  }
  __shared__ float rs[256], rss[256];
  rs[threadIdx.x] = s; rss[threadIdx.x] = ss;
  __syncthreads();
  for (int off = 128; off > 0; off >>= 1){
    if (threadIdx.x < off){ rs[threadIdx.x] += rs[threadIdx.x+off]; rss[threadIdx.x] += rss[threadIdx.x+off]; }
    __syncthreads();
  }
  if (threadIdx.x == 0){ sum[bi] = rs[0]; sumsq[bi] = rss[0]; }
}

// inorm(1e-3) + bnorm(1e-5) collapse: per (b,i) m and combined scale s
__global__ void k_xscale(const float* __restrict__ sum, const float* __restrict__ sumsq,
                         float* __restrict__ mOut, float* __restrict__ sOut){
  int i = threadIdx.x;                       // channel 0..255
  float vl[NB], ml[NB];
  float V = 0.f;
  for (int b = 0; b < NB; b++){
    int bi = b*CIx + i;
    float m = sum[bi] * (1.f/(float)NKx);
    float v = sumsq[bi] * (1.f/(float)NKx) - m*m;
    ml[b] = m; vl[b] = v;
    V += v / (v + 1e-3f);
  }
  V *= (1.f/(float)NB);
  float bs = rsqrtf(V + 1e-5f);
  for (int b = 0; b < NB; b++){
    int bi = b*CIx + i;
    mOut[bi] = ml[b];
    sOut[bi] = rsqrtf(vl[b] + 1e-3f) * bs;
  }
}

// ---- fold wk@w_att1 / wv@w_att1 into Wf[r][i] bf16 (r<128:K, r>=128:V), row-major ----
__global__ void k_prep_kv(const float* __restrict__ w_att1, const float* __restrict__ wk,
                          const float* __restrict__ wv, const float* __restrict__ b_att1,
                          const float* __restrict__ bk, const float* __restrict__ bv,
                          ushort* __restrict__ Wf, float* __restrict__ bKV){
  int r = blockIdx.x;   // 0..255
  int i = threadIdx.x;  // 0..255
  const float* wr = (r < 128) ? (wk + r*128) : (wv + (r-128)*128);
  float acc = 0.f;
  for (int c = 0; c < 128; c++) acc += wr[c] * w_att1[c*CIx + i];
  Wf[r*256 + i] = f2bf(acc);
  if (i == 0){
    float bacc = (r < 128) ? bk[r] : bv[r-128];
    for (int c = 0; c < 128; c++) bacc += wr[c] * b_att1[c];
    bKV[r] = bacc;
  }
}

// ---- pack conv weights to bf16 [r][i] + stacked bias2 ----
__global__ void k_prepW(const float* __restrict__ wq, const float* __restrict__ w_right,
                        const float* __restrict__ w_l1, const float* __restrict__ w_l2,
                        const float* __restrict__ w_l3, const float* __restrict__ b_right,
                        const float* __restrict__ b_l1,
                        ushort* __restrict__ Wq, ushort* __restrict__ W2,
                        ushort* __restrict__ W3, ushort* __restrict__ W4,
                        float* __restrict__ bias2){
  int idx = blockIdx.x*256 + threadIdx.x;
  if (idx < 16384){ Wq[idx] = f2bf(wq[idx]); return; }
  idx -= 16384;
  if (idx < 65536){
    int r = idx >> 8, i = idx & 255;
    W2[idx] = f2bf(r < 128 ? w_right[r*256+i] : w_l1[(r-128)*256+i]);
    return;
  }
  idx -= 65536;
  if (idx < 16384){ W3[idx] = f2bf(w_l2[idx]); return; }
  idx -= 16384;
  if (idx < 16384){ W4[idx] = f2bf(w_l3[idx]); return; }
  idx -= 16384;
  if (idx < 256) bias2[idx] = (idx < 128) ? b_right[idx] : b_l1[idx-128];
}

// ---------------- fused MFMA attention, 8-n tile (72 cols padded to 80) ----------------
// D[colx][r] = sum_i relu((x[i][col]-m_i)*s_i) * Wf[r][i]   (C^T orientation)
// x read from L3-resident bf16 copy; whole 256-i window staged once;
// 160 MFMAs barrier-free; acc = 80 regs/thread.
__global__ __launch_bounds__(256,3) void k_attn_mfma(
    const ushort* __restrict__ xlb,
    const float* __restrict__ mArr, const float* __restrict__ sArr,
    const ushort* __restrict__ Wf, const float* __restrict__ bKV,
    const float* __restrict__ Pq,
    float* __restrict__ out_local)
{
  const int b   = blockIdx.y;
  const int n0  = blockIdx.x * 8;
  const int col0 = n0 * KW;                 // 72 * blockIdx.x
  const int tid = threadIdx.x;
  const int w   = tid >> 6;
  const int lane = tid & 63;
  const int c16 = lane & 15, g = lane >> 4;

  __shared__ ushort wlds[20480];            // 40960B: frag staging; aliased after main loop
  ushort (*elds)[16][72] = (ushort (*)[16][72])wlds;   // 36864B: [w*4+j][c16][col]
  float* obuf = (float*)(wlds + 18432);     // last 4096B: [128][8] coalescing buffer

  // zero the pad region (mt=4, cj 8..15) once
  {
    unsigned* fb = (unsigned*)wlds;
#pragma unroll
    for (int zz = 0; zz < 4; zz++){
      int z = tid + 256*zz;                 // 0..1023
      int io2 = z & 3, cj = 8 + ((z>>2)&7), g_ = (z>>5)&3, s = z>>7;
      fb[((s*5 + 4)*4 + g_)*64 + pi16(cj,4)*4 + io2] = 0u;
    }
  }

  // ---- stage 256 i x 72 cols from bf16 copy: us8 reads, relu((x-m)*s), RNE bf16 ----
  {
    const ushort* xb = xlb + (size_t)b*CIx*NKx + col0;
    const float* mB = mArr + b*CIx;
    const float* sB = sArr + b*CIx;
#pragma unroll
    for (int kk = 0; kk < 5; kk++){
      int idx = tid + 256*kk;               // 0..1151 = 128 i-pairs x 9 c8
      if (idx < 1152){
        int il = idx / 9;
        int c8 = idx - 9*il;
        int i_l = 2*il;
        const ushort* gp = xb + (size_t)i_l*NKx + 8*c8;
        us8 r0 = *(const us8*)gp;
        us8 r1 = *(const us8*)(gp + NKx);
        float2 mm = *(const float2*)(mB + i_l);
        float2 ssv = *(const float2*)(sB + i_l);
        int s = i_l >> 5, g_ = (i_l >> 3) & 3, io2 = il & 3;
        int mt = c8 >> 1;
        int cjb = (c8 & 1) * 8;
        unsigned* dstb = (unsigned*)wlds + ((s*5 + mt)*4 + g_)*64 + io2;
#pragma unroll
        for (int j = 0; j < 8; j++){
          float x0 = bf2f(r0[j]), x1 = bf2f(r1[j]);
          float v0 = fmaxf((x0 - mm.x)*ssv.x, 0.f);
          float v1 = fmaxf((x1 - mm.y)*ssv.y, 0.f);
          dstb[pi16(cjb + j, mt)*4] = (unsigned)f2bf(v0) | ((unsigned)f2bf(v1) << 16);
        }
      }
    }
  }
  __syncthreads();

  // ---- accumulators init AFTER staging ----
  f32x4 acc[5][4];
#pragma unroll
  for (int mt = 0; mt < 5; mt++)
#pragma unroll
    for (int j = 0; j < 4; j++) acc[mt][j] = (f32x4)0.f;

  // ---- 8 K-steps, 160 MFMAs, no barriers ----
  {
    const int ct0 = w, ct1 = w + 4, ct2 = w + 8, ct3 = w + 12;
#pragma unroll
    for (int s = 0; s < 8; s++){
      bf16x8 wf0 = *(const bf16x8*)(Wf + (ct0*16 + c16)*256 + s*32 + g*8);
      bf16x8 wf1 = *(const bf16x8*)(Wf + (ct1*16 + c16)*256 + s*32 + g*8);
      bf16x8 wf2 = *(const bf16x8*)(Wf + (ct2*16 + c16)*256 + s*32 + g*8);
      bf16x8 wf3 = *(const bf16x8*)(Wf + (ct3*16 + c16)*256 + s*32 + g*8);
#pragma unroll
      for (int mt = 0; mt < 5; mt++){
        bf16x8 af = *(const bf16x8*)(wlds + ((s*5 + mt)*4 + g)*128 + pi16(c16, mt)*8);
        acc[mt][0] = __builtin_amdgcn_mfma_f32_16x16x32_bf16(af, wf0, acc[mt][0], 0,0,0);
        acc[mt][1] = __builtin_amdgcn_mfma_f32_16x16x32_bf16(af, wf1, acc[mt][1], 0,0,0);
        acc[mt][2] = __builtin_amdgcn_mfma_f32_16x16x32_bf16(af, wf2, acc[mt][2], 0,0,0);
        acc[mt][3] = __builtin_amdgcn_mfma_f32_16x16x32_bf16(af, wf3, acc[mt][3], 0,0,0);
      }
    }
  }
  __syncthreads();    // staging dead; elds/obuf alias it from here

  // ---- q + biases ----
  const int chA = w*16 + c16;
  float2 qa, qb;
  {
    const float* p0 = Pq + ((size_t)(b*COx + chA))*NPTS + n0 + 2*g;
    qa = *(const float2*)p0;                 // ch = chA,    points 2g, 2g+1
    qb = *(const float2*)(p0 + 64*NPTS);     // ch = chA+64
  }
  float bk0 = bKV[chA], bk1 = bKV[chA + 64];
  float bv0 = bKV[128 + chA], bv1 = bKV[128 + chA + 64];

  // ---- dump all 4 j to elds (bf16), single barrier ----
#pragma unroll
  for (int mt = 0; mt < 5; mt++){
    if (mt < 4 || g < 2){
      int colb = 16*mt + 4*g;
#pragma unroll
      for (int j = 0; j < 4; j++){
#pragma unroll
        for (int r2 = 0; r2 < 2; r2++){
          unsigned pk = (unsigned)f2bf(acc[mt][j][2*r2]) | ((unsigned)f2bf(acc[mt][j][2*r2+1]) << 16);
          *(unsigned*)&elds[w*4 + j][c16][colb + 2*r2] = pk;
        }
      }
    }
  }
  __syncthreads();

  // ---- softmax over K=9 + PV, both ch halves ----
#pragma unroll
  for (int h = 0; h < 2; h++){
    float bk_ = h ? bk1 : bk0;
    float bv_ = h ? bv1 : bv0;
    int ch = chA + 64*h;
    const ushort* eK = &elds[w*4 + h][c16][0];
    const ushort* eV = &elds[w*4 + 2 + h][c16][0];
#pragma unroll
    for (int t = 0; t < 2; t++){
      int nloc = 2*g + t;
      int cb = 9*nloc;
      float qq = h ? (t ? qb.y : qb.x) : (t ? qa.y : qa.x);
      float sc[KW];
      float mx = -1e30f;
#pragma unroll
      for (int k = 0; k < KW; k++){
        float s_ = qq * (bf2f(eK[cb + k]) + bk_);
        sc[k] = s_;
        mx = fmaxf(mx, s_);
      }
      float den = 0.f, num = 0.f;
#pragma unroll
      for (int k = 0; k < KW; k++){
        float e = __expf(sc[k] - mx);
        den += e;
        num += e * (bf2f(eV[cb + k]) + bv_);
      }
      obuf[ch*8 + nloc] = num / den;
    }
  }
  __syncthreads();

  // ---- coalesced store: 2 threads per channel ----
  {
    int ch = tid >> 1, part = tid & 1;
    float4 v = *(float4*)&obuf[ch*8 + 4*part];
    *(float4*)(out_local + ((size_t)(b*COx + ch))*NPTS + n0 + 4*part) = v;
  }
}

// ---------------- generic MFMA conv1x1 over n-tiles of 80 ----------------
// MODE 0: q; MODE 1: conv2x + stats(c1); MODE 2: c2 (+uout, stats); MODE 3: c3 (stats)
template<int MODE>
__global__ __launch_bounds__(256) void k_mconv(
    const float* __restrict__ inA, const float* __restrict__ inB,
    const ushort* __restrict__ Wc, const float* __restrict__ bias,
    const float* __restrict__ nm, const float* __restrict__ nsc,
    float* __restrict__ out0, float* __restrict__ out1,
    float* __restrict__ uout, float* __restrict__ pstat)
{
  constexpr int IC = (MODE==1) ? 256 : 128;
  constexpr int RC = (MODE==1) ? 256 : 128;
  constexpr int NS = IC/32;
  constexpr int JW = RC/64;
  constexpr int PHASES = RC/128;
  constexpr bool STATS = (MODE >= 1);
  constexpr int SPH = (MODE==1) ? 1 : 0;

  const int b = blockIdx.y, bx = blockIdx.x;
  const int n0 = bx*80;
  const int tid = threadIdx.x;
  const int w = tid>>6, lane = tid&63;
  const int c16 = lane&15, g = lane>>4;

  __shared__ ushort smem[21504];

  {
    constexpr int TOT = (IC/2)*20;
    const float* srcA = inA + (size_t)b*128*NPTS;
    const float* srcB = inB ? (inB + (size_t)b*128*NPTS) : nullptr;
    for (int idx = tid; idx < TOT; idx += 256){
      int pr = idx/20, c4 = idx - 20*pr;
      int i = pr*2;
      int cc = n0 + 4*c4;
      float4 va, vb;
      if (MODE == 0){
        const float* base = srcA + (size_t)i*NPTS + cc;
        va = *(const float4*)base;
        vb = *(const float4*)(base + NPTS);
      } else if (MODE == 1){
        const float* base = (i < 128) ? (srcA + (size_t)i*NPTS + cc)
                                      : (srcB + (size_t)(i-128)*NPTS + cc);
        va = *(const float4*)base;
        vb = *(const float4*)(base + NPTS);
      } else {
        const float* pa = srcA + (size_t)i*NPTS + cc;
        const float* pb = srcB + (size_t)i*NPTS + cc;
        float4 ca = *(const float4*)pa, cb = *(const float4*)(pa+NPTS);
        float4 aa = *(const float4*)pb, ab = *(const float4*)(pb+NPTS);
        float m0 = nm[b*128+i],   s0 = nsc[b*128+i];
        float m1 = nm[b*128+i+1], s1 = nsc[b*128+i+1];
        va.x = fmaxf((ca.x-m0)*s0,0.f)+aa.x; va.y = fmaxf((ca.y-m0)*s0,0.f)+aa.y;
        va.z = fmaxf((ca.z-m0)*s0,0.f)+aa.z; va.w = fmaxf((ca.w-m0)*s0,0.f)+aa.w;
        vb.x = fmaxf((cb.x-m1)*s1,0.f)+ab.x; vb.y = fmaxf((cb.y-m1)*s1,0.f)+ab.y;
        vb.z = fmaxf((cb.z-m1)*s1,0.f)+ab.z; vb.w = fmaxf((cb.w-m1)*s1,0.f)+ab.w;
        if (MODE == 2){
          float4 u0, u1;
          u0.x = va.x+aa.x; u0.y = va.y+aa.y; u0.z = va.z+aa.z; u0.w = va.w+aa.w;
          u1.x = vb.x+ab.x; u1.y = vb.y+ab.y; u1.z = vb.z+ab.z; u1.w = vb.w+ab.w;
          *(float4*)(uout + ((size_t)(b*128+i))*NPTS + cc) = u0;
          *(float4*)(uout + ((size_t)(b*128+i+1))*NPTS + cc) = u1;
        }
      }
      int sp = i>>5, g_ = (i>>3)&3, io2 = (i>>1)&3;
      int mt = c4>>2;
      unsigned* dstb = (unsigned*)smem + ((sp*5 + mt)*4 + g_)*64 + io2;
      float a0[4] = {va.x, va.y, va.z, va.w};
      float a1[4] = {vb.x, vb.y, vb.z, vb.w};
#pragma unroll
      for (int j = 0; j < 4; j++){
        int cj = (4*c4 + j) & 15;
        int pi = pi16(cj, mt);
        dstb[pi*4] = (unsigned)f2bf(a0[j]) | ((unsigned)f2bf(a1[j]) << 16);
      }
    }
  }
  __syncthreads();

  f32x4 acc[5][JW];
#pragma unroll
  for (int mt = 0; mt < 5; mt++)
#pragma unroll
    for (int j = 0; j < JW; j++) acc[mt][j] = (f32x4)0.f;

  for (int s = 0; s < NS; s++){
    bf16x8 wf[JW];
#pragma unroll
    for (int j = 0; j < JW; j++)
      wf[j] = *(const bf16x8*)(Wc + ((w + 4*j)*16 + c16)*IC + s*32 + g*8);
#pragma unroll
    for (int mt = 0; mt < 5; mt++){
      bf16x8 af = *(const bf16x8*)(smem + ((s*5 + mt)*4 + g)*128 + pi16(c16, mt)*8);
#pragma unroll
      for (int j = 0; j < JW; j++)
        acc[mt][j] = __builtin_amdgcn_mfma_f32_16x16x32_bf16(af, wf[j], acc[mt][j], 0,0,0);
    }
  }

  float* dl = (float*)smem;
#pragma unroll
  for (int ph = 0; ph < PHASES; ph++){
    __syncthreads();
    float st_s[2], st_ss[2];
#pragma unroll
    for (int jj = 0; jj < 2; jj++){
      int j = ph*2 + jj;
      int ct = w + 4*j;
      int rl = (ct & 7)*16 + c16;
      float bb = bias[ct*16 + c16];
      float s = 0.f, ss = 0.f;
#pragma unroll
      for (int mt = 0; mt < 5; mt++){
        f32x4 v = acc[mt][j];
        float4 vv;
        vv.x = v[0]+bb; vv.y = v[1]+bb; vv.z = v[2]+bb; vv.w = v[3]+bb;
        *(float4*)&dl[rl*84 + mt*16 + 4*g] = vv;
        s  += vv.x + vv.y + vv.z + vv.w;
        ss += vv.x*vv.x + vv.y*vv.y + vv.z*vv.z + vv.w*vv.w;
      }
      st_s[jj] = s; st_ss[jj] = ss;
    }
    if (STATS && ph == SPH){
#pragma unroll
      for (int jj = 0; jj < 2; jj++){
        float s = st_s[jj], ss = st_ss[jj];
        s += __shfl_xor(s, 16); ss += __shfl_xor(ss, 16);
        s += __shfl_xor(s, 32); ss += __shfl_xor(ss, 32);
        if (g == 0){
          int ct = w + 4*(ph*2 + jj);
          int rl = (ct & 7)*16 + c16;
          int off = (b*NTIL + bx)*128 + rl;
          pstat[off]           = s;
          pstat[PSTRIDE + off] = ss;
        }
      }
    }
    __syncthreads();
    float* dst = ph ? out1 : out0;
#pragma unroll
    for (int kk = 0; kk < 10; kk++){
      int idx = kk*256 + tid;
      int r = idx/20, c4 = idx - 20*r;
      *(float4*)(dst + ((size_t)(b*128 + r))*NPTS + n0 + 4*c4) = *(float4*)&dl[r*84 + 4*c4];
    }
  }
}

// ---- reduce pstat -> per-(b,c) m and combined inorm(1e-5)+bnorm scale (parallel) ----
__global__ __launch_bounds__(1024) void k_red(const float* __restrict__ pstat,
                                              float* __restrict__ cm, float* __restrict__ cs){
  __shared__ float msh[2048], vsh[2048], wsh[2048];
  int t = threadIdx.x;
#pragma unroll
  for (int h = 0; h < 2; h++){
    int p = t + h*1024;
    int b = p >> 7, c = p & 127;
    float s = 0.f, ss = 0.f;
    for (int tt = 0; tt < NTIL; tt++){
      int off = (b*NTIL + tt)*128 + c;
      s  += pstat[off];
      ss += pstat[PSTRIDE + off];
    }
    float m = s * (1.f/(float)NPTS);
    float v = ss * (1.f/(float)NPTS) - m*m;
    msh[p] = m; vsh[p] = v; wsh[p] = v/(v + 1e-5f);
  }
  __syncthreads();
  if (t < 128){
    float V = 0.f;
    for (int b = 0; b < NB; b++) V += wsh[b*128 + t];
    float bs = rsqrtf(V*(1.f/(float)NB) + 1e-5f);
    for (int b = 0; b < NB; b++){
      cm[b*COx + t] = msh[b*128 + t];
      cs[b*COx + t] = rsqrtf(vsh[b*128 + t] + 1e-5f) * bs;
    }
  }
}

// o3 = relu(norm(c3)+x1); t = x_row + g*o3; out = 0.5*(t + mean_c t)
__global__ __launch_bounds__(256) void k_final(const float* __restrict__ c3, const float* __restrict__ x1,
    const float* __restrict__ x_row, const float* __restrict__ cm, const float* __restrict__ cs,
    const float* __restrict__ gamma1, float* __restrict__ out)
{
  const int b  = blockIdx.y;
  const int n0 = blockIdx.x * 50;
  const int tid = threadIdx.x;
  const float g = gamma1[0];
  __shared__ float tt[128][50];
  __shared__ float part[4][50];
  for (int idx = tid; idx < 128*50; idx += 256){
    int c = idx / 50; int j = idx - c*50;
    size_t off = ((size_t)b*COx + c)*NPTS + n0 + j;
    float o3 = fmaxf((c3[off] - cm[b*COx + c]) * cs[b*COx + c] + x1[off], 0.f);
    tt[c][j] = x_row[off] + g * o3;
  }
  __syncthreads();
  if (tid < 200){
    int gg = tid / 50, j = tid - gg*50;
    float s = 0.f;
    for (int c = gg*32; c < gg*32 + 32; c++) s += tt[c][j];
    part[gg][j] = s;
  }
  __syncthreads();
  for (int idx = tid; idx < 128*50; idx += 256){
    int c = idx / 50; int j = idx - c*50;
    float mean = (part[0][j] + part[1][j] + part[2][j] + part[3][j]) * (1.f/128.f);
    out[((size_t)b*COx + c)*NPTS + n0 + j] = 0.5f * (tt[c][j] + mean);
  }
}

extern "C" void kernel_launch(void* const* d_in, const int* in_sizes, int n_in,
                              void* d_out, int out_size, void* d_ws, size_t ws_size,
                              hipStream_t stream){
  (void)in_sizes; (void)n_in; (void)out_size; (void)ws_size;
  const float* x_row   = (const float*)d_in[0];
  const float* x_local = (const float*)d_in[1];
  const float* w_att1  = (const float*)d_in[2];
  const float* b_att1  = (const float*)d_in[3];
  const float* wq      = (const float*)d_in[4];
  const float* bq      = (const float*)d_in[5];
  const float* wk      = (const float*)d_in[6];
  const float* bk      = (const float*)d_in[7];
  const float* wv      = (const float*)d_in[8];
  const float* bv      = (const float*)d_in[9];
  const float* w_right = (const float*)d_in[10];
  const float* b_right = (const float*)d_in[11];
  const float* w_l1    = (const float*)d_in[12];
  const float* b_l1    = (const float*)d_in[13];
  const float* w_l2    = (const float*)d_in[14];
  const float* b_l2    = (const float*)d_in[15];
  const float* w_l3    = (const float*)d_in[16];
  const float* b_l3    = (const float*)d_in[17];
  const float* gamma1  = (const float*)d_in[18];
  float* out = (float*)d_out;

  float*  ws     = (float*)d_ws;
  float*  sum    = ws;                        // 4096
  float*  sumsq  = ws + 4096;                 // 4096
  float*  mArr   = ws + 8192;                 // 4096
  float*  sArr   = ws + 12288;                // 4096
  ushort* Wf     = (ushort*)(ws + 16384);     // 65536 us = 32768 floats
  float*  bKV    = ws + 49152;                // 256
  ushort* Wq     = (ushort*)(ws + 49408);     // 16384 us
  ushort* W2     = (ushort*)(ws + 57600);     // 65536 us
  ushort* W3     = (ushort*)(ws + 90368);     // 16384 us
  ushort* W4     = (ushort*)(ws + 98560);     // 16384 us
  float*  bias2  = ws + 106752;               // 256
  float*  cm     = ws + 107008;               // 2048
  float*  cs     = ws + 109056;               // 2048
  float*  pstat  = ws + 111104;               // 102400 (s plane + ss plane)
  float*  P0 = ws + 262144;                   // 4,096,000 each
  float*  P1 = P0 + 4096000;
  float*  P2 = P1 + 4096000;
  float*  P3 = P2 + 4096000;
  ushort* xlb = (ushort*)(P3 + 4096000);      // 73,728,000 us = 147.5 MB (L3-resident)

  // stats + free bf16 copy of x_local, then weight prep
  k_xstats <<<4096, 256, 0, stream>>>(x_local, sum, sumsq, xlb);
  k_xscale <<<1, 256, 0, stream>>>(sum, sumsq, mArr, sArr);
  k_prep_kv<<<256, 256, 0, stream>>>(w_att1, wk, wv, b_att1, bk, bv, Wf, bKV);
  k_prepW  <<<450, 256, 0, stream>>>(wq, w_right, w_l1, w_l2, w_l3, b_right, b_l1,
                                     Wq, W2, W3, W4, bias2);

  // q = wq . x_row + bq -> P1
  k_mconv<0><<<dim3(NTIL, NB), 256, 0, stream>>>(x_row, nullptr, Wq, bq,
                                                 nullptr, nullptr, P1, nullptr, nullptr, nullptr);

  // fused MFMA attention -> out_local (P0)
  k_attn_mfma<<<dim3(250, NB), 256, 0, stream>>>(xlb, mArr, sArr, Wf, bKV, P1, P0);

  // x1 (P1), c1 (P2) + stats(c1)
  k_mconv<1><<<dim3(NTIL, NB), 256, 0, stream>>>(x_row, P0, W2, bias2,
                                                 nullptr, nullptr, P1, P2, nullptr, pstat);
  k_red<<<1, 1024, 0, stream>>>(pstat, cm, cs);

  // stage o1 = relu(norm(c1))+x1; c2 (P3); u = o1+x1 -> P0; stats(c2)
  k_mconv<2><<<dim3(NTIL, NB), 256, 0, stream>>>(P2, P1, W3, b_l2,
                                                 cm, cs, P3, nullptr, P0, pstat);
  k_red<<<1, 1024, 0, stream>>>(pstat, cm, cs);

  // stage o2 = relu(norm(c2))+u; c3 (P2); stats(c3)
  k_mconv<3><<<dim3(NTIL, NB), 256, 0, stream>>>(P3, P0, W4, b_l3,
                                                 cm, cs, P2, nullptr, nullptr, pstat);
  k_red<<<1, 1024, 0, stream>>>(pstat, cm, cs);

  // final
  k_final<<<dim3(NPTS/50, NB), 256, 0, stream>>>(P2, P1, x_row, cm, cs, gamma1, out);
}

// Round 13
// 310.253 us; speedup vs baseline: 1.0214x; 1.0214x over previous
//
#include <hip/hip_runtime.h>
#include <math.h>

#define NB    16
#define CIx   256
#define COx   128
#define NPTS  2000
#define KW    9
#define NKx   18000   // NPTS*KW
#define NTIL  25      // n tiles of 80 for mconv
#define PSTRIDE 51200 // NB*NTIL*128

typedef short bf16x8 __attribute__((ext_vector_type(8)));
typedef float f32x4  __attribute__((ext_vector_type(4)));

__device__ __forceinline__ ushort f2bf(float f){
  unsigned u = __builtin_bit_cast(unsigned, f);
  u = (u + 0x7fffu + ((u>>16)&1u)) >> 16;
  return (ushort)u;
}
__device__ __forceinline__ float bf2f(ushort h){
  unsigned u = ((unsigned)h)<<16;
  return __builtin_bit_cast(float, u);
}
// per-mt within-slot placement permutation: bijective, puts mt parity into bank bit 4
__device__ __forceinline__ int pi16(int c, int mt){
  return (((c & 3) ^ (mt & 3)) << 2) | (c >> 2);
}

// ---------------- stats over x_local: per (b,i) sum/sumsq over 18000 ----------------
__global__ __launch_bounds__(256) void k_xstats(const float* __restrict__ xl,
    float* __restrict__ sum, float* __restrict__ sumsq){
  int bi = blockIdx.x;                       // b*256 + i
  const float4* p = (const float4*)(xl + (size_t)bi * NKx);
  float s = 0.f, ss = 0.f;
  for (int idx = threadIdx.x; idx < NKx/4; idx += 256){
    float4 v = p[idx];
    s  += v.x + v.y + v.z + v.w;
    ss += v.x*v.x + v.y*v.y + v.z*v.z + v.w*v.w;
  }
  __shared__ float rs[256], rss[256];
  rs[threadIdx.x] = s; rss[threadIdx.x] = ss;
  __syncthreads();
  for (int off = 128; off > 0; off >>= 1){
    if (threadIdx.x < off){ rs[threadIdx.x] += rs[threadIdx.x+off]; rss[threadIdx.x] += rss[threadIdx.x+off]; }
    __syncthreads();
  }
  if (threadIdx.x == 0){ sum[bi] = rs[0]; sumsq[bi] = rss[0]; }
}

// inorm(1e-3) + bnorm(1e-5) collapse: per (b,i) m and combined scale s
__global__ void k_xscale(const float* __restrict__ sum, const float* __restrict__ sumsq,
                         float* __restrict__ mOut, float* __restrict__ sOut){
  int i = threadIdx.x;                       // channel 0..255
  float vl[NB], ml[NB];
  float V = 0.f;
  for (int b = 0; b < NB; b++){
    int bi = b*CIx + i;
    float m = sum[bi] * (1.f/(float)NKx);
    float v = sumsq[bi] * (1.f/(float)NKx) - m*m;
    ml[b] = m; vl[b] = v;
    V += v / (v + 1e-3f);
  }
  V *= (1.f/(float)NB);
  float bs = rsqrtf(V + 1e-5f);
  for (int b = 0; b < NB; b++){
    int bi = b*CIx + i;
    mOut[bi] = ml[b];
    sOut[bi] = rsqrtf(vl[b] + 1e-3f) * bs;
  }
}

// ---- fold wk@w_att1 / wv@w_att1 into Wf[r][i] bf16 (r<128:K, r>=128:V), row-major ----
__global__ void k_prep_kv(const float* __restrict__ w_att1, const float* __restrict__ wk,
                          const float* __restrict__ wv, const float* __restrict__ b_att1,
                          const float* __restrict__ bk, const float* __restrict__ bv,
                          ushort* __restrict__ Wf, float* __restrict__ bKV){
  int r = blockIdx.x;   // 0..255
  int i = threadIdx.x;  // 0..255
  const float* wr = (r < 128) ? (wk + r*128) : (wv + (r-128)*128);
  float acc = 0.f;
  for (int c = 0; c < 128; c++) acc += wr[c] * w_att1[c*CIx + i];
  Wf[r*256 + i] = f2bf(acc);
  if (i == 0){
    float bacc = (r < 128) ? bk[r] : bv[r-128];
    for (int c = 0; c < 128; c++) bacc += wr[c] * b_att1[c];
    bKV[r] = bacc;
  }
}

// ---- pack conv weights to bf16 [r][i] + stacked bias2 ----
__global__ void k_prepW(const float* __restrict__ wq, const float* __restrict__ w_right,
                        const float* __restrict__ w_l1, const float* __restrict__ w_l2,
                        const float* __restrict__ w_l3, const float* __restrict__ b_right,
                        const float* __restrict__ b_l1,
                        ushort* __restrict__ Wq, ushort* __restrict__ W2,
                        ushort* __restrict__ W3, ushort* __restrict__ W4,
                        float* __restrict__ bias2){
  int idx = blockIdx.x*256 + threadIdx.x;
  if (idx < 16384){ Wq[idx] = f2bf(wq[idx]); return; }
  idx -= 16384;
  if (idx < 65536){
    int r = idx >> 8, i = idx & 255;
    W2[idx] = f2bf(r < 128 ? w_right[r*256+i] : w_l1[(r-128)*256+i]);
    return;
  }
  idx -= 65536;
  if (idx < 16384){ W3[idx] = f2bf(w_l2[idx]); return; }
  idx -= 16384;
  if (idx < 16384){ W4[idx] = f2bf(w_l3[idx]); return; }
  idx -= 16384;
  if (idx < 256) bias2[idx] = (idx < 128) ? b_right[idx] : b_l1[idx-128];
}

// ---------------- fused MFMA attention + q-conv, 8-n tile ----------------
// D[colx][r] = sum_i relu((x[i][col]-m_i)*s_i) * Wf[r][i]   (C^T orientation)
// q = Wq . x_row + bq computed in-kernel (8 MFMAs/wave) -> qbuf exchange.
__global__ __launch_bounds__(256,3) void k_attn_mfma(
    const float* __restrict__ xl, const float* __restrict__ x_row,
    const float* __restrict__ mArr, const float* __restrict__ sArr,
    const ushort* __restrict__ Wf, const float* __restrict__ bKV,
    const ushort* __restrict__ Wq, const float* __restrict__ bq,
    float* __restrict__ out_local)
{
  const int b   = blockIdx.y;
  const int n0  = blockIdx.x * 8;
  const int col0 = n0 * KW;                 // 72 * blockIdx.x
  const int tid = threadIdx.x;
  const int w   = tid >> 6;
  const int lane = tid & 63;
  const int c16 = lane & 15, g = lane >> 4;

  __shared__ ushort wlds[20480];            // 40960B: frag staging; aliased after main loop
  __shared__ ushort qlds[2048];             // 4096B: x_row frags for q-GEMM
  __shared__ float  qbuf[128*8];            // 4096B: q exchange
  ushort (*elds)[16][72] = (ushort (*)[16][72])wlds;   // 36864B: [w*4+j][c16][col]
  float* obuf = (float*)(wlds + 18432);     // last 4096B of wlds: [128][8] out buffer

  // zero the pad region (mt=4, cj 8..15) once
  {
    unsigned* fb = (unsigned*)wlds;
#pragma unroll
    for (int zz = 0; zz < 4; zz++){
      int z = tid + 256*zz;                 // 0..1023
      int io2 = z & 3, cj = 8 + ((z>>2)&7), g_ = (z>>5)&3, s = z>>7;
      fb[((s*5 + 4)*4 + g_)*64 + pi16(cj,4)*4 + io2] = 0u;
    }
  }

  // ---- stage x_row[128][8] -> qlds frags (bf16); zero cols 8..15 ----
  {
    int row = tid >> 1, half = tid & 1;
    const float* xr = x_row + ((size_t)(b*COx + row))*NPTS + n0 + 4*half;
    float4 v = *(const float4*)xr;
    int kq = row >> 5, g_ = (row >> 3) & 3, io = row & 7;
    int base = (kq*4 + g_)*128 + io;        // + cj*8
    float a[4] = {v.x, v.y, v.z, v.w};
#pragma unroll
    for (int j = 0; j < 4; j++){
      qlds[base + (4*half + j)*8] = f2bf(a[j]);
      qlds[base + (8 + 4*half + j)*8] = 0;
    }
  }

  // ---- stage 256 i x 72 cols: float4 reads, relu((x-m)*s), RNE bf16, pi16 LDS ----
  {
    const size_t xb = (size_t)b*CIx*NKx + col0;
    const float* mB = mArr + b*CIx;
    const float* sB = sArr + b*CIx;
#pragma unroll
    for (int kk = 0; kk < 9; kk++){
      int idx = tid + 256*kk;               // 0..2303 = 128 i-pairs x 18 c4
      int il  = idx / 18;
      int c4  = idx - 18*il;
      int i_l = 2*il;
      int col = 4*c4;
      const float* gp = xl + xb + (size_t)i_l*NKx + col;
      float4 ra = *(const float4*)gp;
      float4 rb = *(const float4*)(gp + NKx);
      float2 mm = *(const float2*)(mB + i_l);
      float2 ssv = *(const float2*)(sB + i_l);
      int s = i_l >> 5, g_ = (i_l >> 3) & 3, io2 = il & 3;
      int mt = c4 >> 2;
      unsigned* dstb = (unsigned*)wlds + ((s*5 + mt)*4 + g_)*64 + io2;
      float a0[4] = {ra.x, ra.y, ra.z, ra.w};
      float a1[4] = {rb.x, rb.y, rb.z, rb.w};
#pragma unroll
      for (int j = 0; j < 4; j++){
        int cj = (col + j) & 15;
        float v0 = fmaxf((a0[j] - mm.x)*ssv.x, 0.f);
        float v1 = fmaxf((a1[j] - mm.y)*ssv.y, 0.f);
        dstb[pi16(cj, mt)*4] = (unsigned)f2bf(v0) | ((unsigned)f2bf(v1) << 16);
      }
    }
  }
  __syncthreads();

  // ---- accumulators init AFTER staging ----
  f32x4 acc[5][4];
#pragma unroll
  for (int mt = 0; mt < 5; mt++)
#pragma unroll
    for (int j = 0; j < 4; j++) acc[mt][j] = (f32x4)0.f;

  // ---- 8 K-steps, 160 MFMAs, no barriers ----
  {
    const int ct0 = w, ct1 = w + 4, ct2 = w + 8, ct3 = w + 12;
#pragma unroll
    for (int s = 0; s < 8; s++){
      bf16x8 wf0 = *(const bf16x8*)(Wf + (ct0*16 + c16)*256 + s*32 + g*8);
      bf16x8 wf1 = *(const bf16x8*)(Wf + (ct1*16 + c16)*256 + s*32 + g*8);
      bf16x8 wf2 = *(const bf16x8*)(Wf + (ct2*16 + c16)*256 + s*32 + g*8);
      bf16x8 wf3 = *(const bf16x8*)(Wf + (ct3*16 + c16)*256 + s*32 + g*8);
#pragma unroll
      for (int mt = 0; mt < 5; mt++){
        bf16x8 af = *(const bf16x8*)(wlds + ((s*5 + mt)*4 + g)*128 + pi16(c16, mt)*8);
        acc[mt][0] = __builtin_amdgcn_mfma_f32_16x16x32_bf16(af, wf0, acc[mt][0], 0,0,0);
        acc[mt][1] = __builtin_amdgcn_mfma_f32_16x16x32_bf16(af, wf1, acc[mt][1], 0,0,0);
        acc[mt][2] = __builtin_amdgcn_mfma_f32_16x16x32_bf16(af, wf2, acc[mt][2], 0,0,0);
        acc[mt][3] = __builtin_amdgcn_mfma_f32_16x16x32_bf16(af, wf3, acc[mt][3], 0,0,0);
      }
    }
  }

  // ---- q-GEMM: 8 MFMAs/wave, channels chA (j=0) and chA+64 (j=1) ----
  f32x4 accq[2];
  accq[0] = (f32x4)0.f; accq[1] = (f32x4)0.f;
  {
#pragma unroll
    for (int kq = 0; kq < 4; kq++){
      bf16x8 afq = *(const bf16x8*)(qlds + (kq*4 + g)*128 + c16*8);
      bf16x8 wq0 = *(const bf16x8*)(Wq + ((w     )*16 + c16)*128 + kq*32 + g*8);
      bf16x8 wq1 = *(const bf16x8*)(Wq + ((w + 4 )*16 + c16)*128 + kq*32 + g*8);
      accq[0] = __builtin_amdgcn_mfma_f32_16x16x32_bf16(afq, wq0, accq[0], 0,0,0);
      accq[1] = __builtin_amdgcn_mfma_f32_16x16x32_bf16(afq, wq1, accq[1], 0,0,0);
    }
  }
  __syncthreads();    // staging dead; elds/obuf alias wlds from here

  const int chA = w*16 + c16;

  // ---- qbuf write (lanes g<2 hold valid cols 0..7) + elds dump, single barrier ----
  if (g < 2){
#pragma unroll
    for (int j = 0; j < 2; j++){
      int ch = chA + 64*j;
      float bb = bq[ch];
#pragma unroll
      for (int r2 = 0; r2 < 4; r2++)
        qbuf[ch*8 + 4*g + r2] = accq[j][r2] + bb;
    }
  }
#pragma unroll
  for (int mt = 0; mt < 5; mt++){
    if (mt < 4 || g < 2){
      int colb = 16*mt + 4*g;
#pragma unroll
      for (int j = 0; j < 4; j++){
#pragma unroll
        for (int r2 = 0; r2 < 2; r2++){
          unsigned pk = (unsigned)f2bf(acc[mt][j][2*r2]) | ((unsigned)f2bf(acc[mt][j][2*r2+1]) << 16);
          *(unsigned*)&elds[w*4 + j][c16][colb + 2*r2] = pk;
        }
      }
    }
  }
  __syncthreads();

  float bk0 = bKV[chA], bk1 = bKV[chA + 64];
  float bv0 = bKV[128 + chA], bv1 = bKV[128 + chA + 64];

  // ---- softmax over K=9 + PV, both ch halves ----
#pragma unroll
  for (int h = 0; h < 2; h++){
    float bk_ = h ? bk1 : bk0;
    float bv_ = h ? bv1 : bv0;
    int ch = chA + 64*h;
    const ushort* eK = &elds[w*4 + h][c16][0];
    const ushort* eV = &elds[w*4 + 2 + h][c16][0];
#pragma unroll
    for (int t = 0; t < 2; t++){
      int nloc = 2*g + t;
      int cb = 9*nloc;
      float qq = qbuf[ch*8 + nloc];
      float sc[KW];
      float mx = -1e30f;
#pragma unroll
      for (int k = 0; k < KW; k++){
        float s_ = qq * (bf2f(eK[cb + k]) + bk_);
        sc[k] = s_;
        mx = fmaxf(mx, s_);
      }
      float den = 0.f, num = 0.f;
#pragma unroll
      for (int k = 0; k < KW; k++){
        float e = __expf(sc[k] - mx);
        den += e;
        num += e * (bf2f(eV[cb + k]) + bv_);
      }
      obuf[ch*8 + nloc] = num / den;
    }
  }
  __syncthreads();

  // ---- coalesced store: 2 threads per channel ----
  {
    int ch = tid >> 1, part = tid & 1;
    float4 v = *(float4*)&obuf[ch*8 + 4*part];
    *(float4*)(out_local + ((size_t)(b*COx + ch))*NPTS + n0 + 4*part) = v;
  }
}

// ---------------- generic MFMA conv1x1 over n-tiles of 80 ----------------
// MODE 1: conv2x + stats(c1); MODE 2: c2 (+uout, stats); MODE 3: c3 (stats)
template<int MODE>
__global__ __launch_bounds__(256) void k_mconv(
    const float* __restrict__ inA, const float* __restrict__ inB,
    const ushort* __restrict__ Wc, const float* __restrict__ bias,
    const float* __restrict__ nm, const float* __restrict__ nsc,
    float* __restrict__ out0, float* __restrict__ out1,
    float* __restrict__ uout, float* __restrict__ pstat)
{
  constexpr int IC = (MODE==1) ? 256 : 128;
  constexpr int RC = (MODE==1) ? 256 : 128;
  constexpr int NS = IC/32;
  constexpr int JW = RC/64;
  constexpr int PHASES = RC/128;
  constexpr bool STATS = (MODE >= 1);
  constexpr int SPH = (MODE==1) ? 1 : 0;

  const int b = blockIdx.y, bx = blockIdx.x;
  const int n0 = bx*80;
  const int tid = threadIdx.x;
  const int w = tid>>6, lane = tid&63;
  const int c16 = lane&15, g = lane>>4;

  __shared__ ushort smem[21504];

  {
    constexpr int TOT = (IC/2)*20;
    const float* srcA = inA + (size_t)b*128*NPTS;
    const float* srcB = inB ? (inB + (size_t)b*128*NPTS) : nullptr;
    for (int idx = tid; idx < TOT; idx += 256){
      int pr = idx/20, c4 = idx - 20*pr;
      int i = pr*2;
      int cc = n0 + 4*c4;
      float4 va, vb;
      if (MODE == 1){
        const float* base = (i < 128) ? (srcA + (size_t)i*NPTS + cc)
                                      : (srcB + (size_t)(i-128)*NPTS + cc);
        va = *(const float4*)base;
        vb = *(const float4*)(base + NPTS);
      } else {
        const float* pa = srcA + (size_t)i*NPTS + cc;
        const float* pb = srcB + (size_t)i*NPTS + cc;
        float4 ca = *(const float4*)pa, cb = *(const float4*)(pa+NPTS);
        float4 aa = *(const float4*)pb, ab = *(const float4*)(pb+NPTS);
        float m0 = nm[b*128+i],   s0 = nsc[b*128+i];
        float m1 = nm[b*128+i+1], s1 = nsc[b*128+i+1];
        va.x = fmaxf((ca.x-m0)*s0,0.f)+aa.x; va.y = fmaxf((ca.y-m0)*s0,0.f)+aa.y;
        va.z = fmaxf((ca.z-m0)*s0,0.f)+aa.z; va.w = fmaxf((ca.w-m0)*s0,0.f)+aa.w;
        vb.x = fmaxf((cb.x-m1)*s1,0.f)+ab.x; vb.y = fmaxf((cb.y-m1)*s1,0.f)+ab.y;
        vb.z = fmaxf((cb.z-m1)*s1,0.f)+ab.z; vb.w = fmaxf((cb.w-m1)*s1,0.f)+ab.w;
        if (MODE == 2){
          float4 u0, u1;
          u0.x = va.x+aa.x; u0.y = va.y+aa.y; u0.z = va.z+aa.z; u0.w = va.w+aa.w;
          u1.x = vb.x+ab.x; u1.y = vb.y+ab.y; u1.z = vb.z+ab.z; u1.w = vb.w+ab.w;
          *(float4*)(uout + ((size_t)(b*128+i))*NPTS + cc) = u0;
          *(float4*)(uout + ((size_t)(b*128+i+1))*NPTS + cc) = u1;
        }
      }
      int sp = i>>5, g_ = (i>>3)&3, io2 = (i>>1)&3;
      int mt = c4>>2;
      unsigned* dstb = (unsigned*)smem + ((sp*5 + mt)*4 + g_)*64 + io2;
      float a0[4] = {va.x, va.y, va.z, va.w};
      float a1[4] = {vb.x, vb.y, vb.z, vb.w};
#pragma unroll
      for (int j = 0; j < 4; j++){
        int cj = (4*c4 + j) & 15;
        int pi = pi16(cj, mt);
        dstb[pi*4] = (unsigned)f2bf(a0[j]) | ((unsigned)f2bf(a1[j]) << 16);
      }
    }
  }
  __syncthreads();

  f32x4 acc[5][JW];
#pragma unroll
  for (int mt = 0; mt < 5; mt++)
#pragma unroll
    for (int j = 0; j < JW; j++) acc[mt][j] = (f32x4)0.f;

  for (int s = 0; s < NS; s++){
    bf16x8 wf[JW];
#pragma unroll
    for (int j = 0; j < JW; j++)
      wf[j] = *(const bf16x8*)(Wc + ((w + 4*j)*16 + c16)*IC + s*32 + g*8);
#pragma unroll
    for (int mt = 0; mt < 5; mt++){
      bf16x8 af = *(const bf16x8*)(smem + ((s*5 + mt)*4 + g)*128 + pi16(c16, mt)*8);
#pragma unroll
      for (int j = 0; j < JW; j++)
        acc[mt][j] = __builtin_amdgcn_mfma_f32_16x16x32_bf16(af, wf[j], acc[mt][j], 0,0,0);
    }
  }

  float* dl = (float*)smem;
#pragma unroll
  for (int ph = 0; ph < PHASES; ph++){
    __syncthreads();
    float st_s[2], st_ss[2];
#pragma unroll
    for (int jj = 0; jj < 2; jj++){
      int j = ph*2 + jj;
      int ct = w + 4*j;
      int rl = (ct & 7)*16 + c16;
      float bb = bias[ct*16 + c16];
      float s = 0.f, ss = 0.f;
#pragma unroll
      for (int mt = 0; mt < 5; mt++){
        f32x4 v = acc[mt][j];
        float4 vv;
        vv.x = v[0]+bb; vv.y = v[1]+bb; vv.z = v[2]+bb; vv.w = v[3]+bb;
        *(float4*)&dl[rl*84 + mt*16 + 4*g] = vv;
        s  += vv.x + vv.y + vv.z + vv.w;
        ss += vv.x*vv.x + vv.y*vv.y + vv.z*vv.z + vv.w*vv.w;
      }
      st_s[jj] = s; st_ss[jj] = ss;
    }
    if (STATS && ph == SPH){
#pragma unroll
      for (int jj = 0; jj < 2; jj++){
        float s = st_s[jj], ss = st_ss[jj];
        s += __shfl_xor(s, 16); ss += __shfl_xor(ss, 16);
        s += __shfl_xor(s, 32); ss += __shfl_xor(ss, 32);
        if (g == 0){
          int ct = w + 4*(ph*2 + jj);
          int rl = (ct & 7)*16 + c16;
          int off = (b*NTIL + bx)*128 + rl;
          pstat[off]           = s;
          pstat[PSTRIDE + off] = ss;
        }
      }
    }
    __syncthreads();
    float* dst = ph ? out1 : out0;
#pragma unroll
    for (int kk = 0; kk < 10; kk++){
      int idx = kk*256 + tid;
      int r = idx/20, c4 = idx - 20*r;
      *(float4*)(dst + ((size_t)(b*128 + r))*NPTS + n0 + 4*c4) = *(float4*)&dl[r*84 + 4*c4];
    }
  }
}

// ---- reduce pstat -> per-(b,c) m and combined inorm(1e-5)+bnorm scale (parallel) ----
__global__ __launch_bounds__(1024) void k_red(const float* __restrict__ pstat,
                                              float* __restrict__ cm, float* __restrict__ cs){
  __shared__ float msh[2048], vsh[2048], wsh[2048];
  int t = threadIdx.x;
#pragma unroll
  for (int h = 0; h < 2; h++){
    int p = t + h*1024;
    int b = p >> 7, c = p & 127;
    float s = 0.f, ss = 0.f;
    for (int tt = 0; tt < NTIL; tt++){
      int off = (b*NTIL + tt)*128 + c;
      s  += pstat[off];
      ss += pstat[PSTRIDE + off];
    }
    float m = s * (1.f/(float)NPTS);
    float v = ss * (1.f/(float)NPTS) - m*m;
    msh[p] = m; vsh[p] = v; wsh[p] = v/(v + 1e-5f);
  }
  __syncthreads();
  if (t < 128){
    float V = 0.f;
    for (int b = 0; b < NB; b++) V += wsh[b*128 + t];
    float bs = rsqrtf(V*(1.f/(float)NB) + 1e-5f);
    for (int b = 0; b < NB; b++){
      cm[b*COx + t] = msh[b*128 + t];
      cs[b*COx + t] = rsqrtf(vsh[b*128 + t] + 1e-5f) * bs;
    }
  }
}

// o3 = relu(norm(c3)+x1); t = x_row + g*o3; out = 0.5*(t + mean_c t)
__global__ __launch_bounds__(256) void k_final(const float* __restrict__ c3, const float* __restrict__ x1,
    const float* __restrict__ x_row, const float* __restrict__ cm, const float* __restrict__ cs,
    const float* __restrict__ gamma1, float* __restrict__ out)
{
  const int b  = blockIdx.y;
  const int n0 = blockIdx.x * 50;
  const int tid = threadIdx.x;
  const float g = gamma1[0];
  __shared__ float tt[128][50];
  __shared__ float part[4][50];
  for (int idx = tid; idx < 128*50; idx += 256){
    int c = idx / 50; int j = idx - c*50;
    size_t off = ((size_t)b*COx + c)*NPTS + n0 + j;
    float o3 = fmaxf((c3[off] - cm[b*COx + c]) * cs[b*COx + c] + x1[off], 0.f);
    tt[c][j] = x_row[off] + g * o3;
  }
  __syncthreads();
  if (tid < 200){
    int gg = tid / 50, j = tid - gg*50;
    float s = 0.f;
    for (int c = gg*32; c < gg*32 + 32; c++) s += tt[c][j];
    part[gg][j] = s;
  }
  __syncthreads();
  for (int idx = tid; idx < 128*50; idx += 256){
    int c = idx / 50; int j = idx - c*50;
    float mean = (part[0][j] + part[1][j] + part[2][j] + part[3][j]) * (1.f/128.f);
    out[((size_t)b*COx + c)*NPTS + n0 + j] = 0.5f * (tt[c][j] + mean);
  }
}

extern "C" void kernel_launch(void* const* d_in, const int* in_sizes, int n_in,
                              void* d_out, int out_size, void* d_ws, size_t ws_size,
                              hipStream_t stream){
  (void)in_sizes; (void)n_in; (void)out_size; (void)ws_size;
  const float* x_row   = (const float*)d_in[0];
  const float* x_local = (const float*)d_in[1];
  const float* w_att1  = (const float*)d_in[2];
  const float* b_att1  = (const float*)d_in[3];
  const float* wq      = (const float*)d_in[4];
  const float* bq      = (const float*)d_in[5];
  const float* wk      = (const float*)d_in[6];
  const float* bk      = (const float*)d_in[7];
  const float* wv      = (const float*)d_in[8];
  const float* bv      = (const float*)d_in[9];
  const float* w_right = (const float*)d_in[10];
  const float* b_right = (const float*)d_in[11];
  const float* w_l1    = (const float*)d_in[12];
  const float* b_l1    = (const float*)d_in[13];
  const float* w_l2    = (const float*)d_in[14];
  const float* b_l2    = (const float*)d_in[15];
  const float* w_l3    = (const float*)d_in[16];
  const float* b_l3    = (const float*)d_in[17];
  const float* gamma1  = (const float*)d_in[18];
  float* out = (float*)d_out;

  float*  ws     = (float*)d_ws;
  float*  sum    = ws;                        // 4096
  float*  sumsq  = ws + 4096;                 // 4096
  float*  mArr   = ws + 8192;                 // 4096
  float*  sArr   = ws + 12288;                // 4096
  ushort* Wf     = (ushort*)(ws + 16384);     // 65536 us = 32768 floats
  float*  bKV    = ws + 49152;                // 256
  ushort* Wq     = (ushort*)(ws + 49408);     // 16384 us
  ushort* W2     = (ushort*)(ws + 57600);     // 65536 us
  ushort* W3     = (ushort*)(ws + 90368);     // 16384 us
  ushort* W4     = (ushort*)(ws + 98560);     // 16384 us
  float*  bias2  = ws + 106752;               // 256
  float*  cm     = ws + 107008;               // 2048
  float*  cs     = ws + 109056;               // 2048
  float*  pstat  = ws + 111104;               // 102400 (s plane + ss plane)
  float*  P0 = ws + 262144;                   // 4,096,000 each
  float*  P1 = P0 + 4096000;
  float*  P2 = P1 + 4096000;
  float*  P3 = P2 + 4096000;

  // stats + weight prep
  k_xstats <<<4096, 256, 0, stream>>>(x_local, sum, sumsq);
  k_xscale <<<1, 256, 0, stream>>>(sum, sumsq, mArr, sArr);
  k_prep_kv<<<256, 256, 0, stream>>>(w_att1, wk, wv, b_att1, bk, bv, Wf, bKV);
  k_prepW  <<<450, 256, 0, stream>>>(wq, w_right, w_l1, w_l2, w_l3, b_right, b_l1,
                                     Wq, W2, W3, W4, bias2);

  // fused MFMA attention (q computed in-kernel) -> out_local (P0)
  k_attn_mfma<<<dim3(250, NB), 256, 0, stream>>>(x_local, x_row, mArr, sArr, Wf, bKV, Wq, bq, P0);

  // x1 (P1), c1 (P2) + stats(c1)
  k_mconv<1><<<dim3(NTIL, NB), 256, 0, stream>>>(x_row, P0, W2, bias2,
                                                 nullptr, nullptr, P1, P2, nullptr, pstat);
  k_red<<<1, 1024, 0, stream>>>(pstat, cm, cs);

  // stage o1 = relu(norm(c1))+x1; c2 (P3); u = o1+x1 -> P0; stats(c2)
  k_mconv<2><<<dim3(NTIL, NB), 256, 0, stream>>>(P2, P1, W3, b_l2,
                                                 cm, cs, P3, nullptr, P0, pstat);
  k_red<<<1, 1024, 0, stream>>>(pstat, cm, cs);

  // stage o2 = relu(norm(c2))+u; c3 (P2); stats(c3)
  k_mconv<3><<<dim3(NTIL, NB), 256, 0, stream>>>(P3, P0, W4, b_l3,
                                                 cm, cs, P2, nullptr, nullptr, pstat);
  k_red<<<1, 1024, 0, stream>>>(pstat, cm, cs);

  // final
  k_final<<<dim3(NPTS/50, NB), 256, 0, stream>>>(P2, P1, x_row, cm, cs, gamma1, out);
}

// Round 14
// 302.653 us; speedup vs baseline: 1.0470x; 1.0251x over previous
//
#include <hip/hip_runtime.h>
#include <math.h>

#define NB    16
#define CIx   256
#define COx   128
#define NPTS  2000
#define KW    9
#define NKx   18000   // NPTS*KW
#define NTIL  25      // n tiles of 80 for mconv
#define PSTRIDE 51200 // NB*NTIL*128

typedef short bf16x8 __attribute__((ext_vector_type(8)));
typedef float f32x4  __attribute__((ext_vector_type(4)));
typedef unsigned int u32x4 __attribute__((ext_vector_type(4)));
typedef unsigned int u32x2 __attribute__((ext_vector_type(2)));

__device__ __forceinline__ ushort f2bf(float f){
  unsigned u = __builtin_bit_cast(unsigned, f);
  u = (u + 0x7fffu + ((u>>16)&1u)) >> 16;
  return (ushort)u;
}
__device__ __forceinline__ float bf2f(ushort h){
  unsigned u = ((unsigned)h)<<16;
  return __builtin_bit_cast(float, u);
}
// per-mt within-slot placement permutation: bijective, puts mt parity into bank bit 4
__device__ __forceinline__ int pi16(int c, int mt){
  return (((c & 3) ^ (mt & 3)) << 2) | (c >> 2);
}

// ---------------- stats over x_local: per (b,i) sum/sumsq over 18000 ----------------
__global__ __launch_bounds__(256) void k_xstats(const float* __restrict__ xl,
    float* __restrict__ sum, float* __restrict__ sumsq){
  int bi = blockIdx.x;                       // b*256 + i
  const float4* p = (const float4*)(xl + (size_t)bi * NKx);
  float s = 0.f, ss = 0.f;
  for (int idx = threadIdx.x; idx < NKx/4; idx += 256){
    float4 v = p[idx];
    s  += v.x + v.y + v.z + v.w;
    ss += v.x*v.x + v.y*v.y + v.z*v.z + v.w*v.w;
  }
  __shared__ float rs[256], rss[256];
  rs[threadIdx.x] = s; rss[threadIdx.x] = ss;
  __syncthreads();
  for (int off = 128; off > 0; off >>= 1){
    if (threadIdx.x < off){ rs[threadIdx.x] += rs[threadIdx.x+off]; rss[threadIdx.x] += rss[threadIdx.x+off]; }
    __syncthreads();
  }
  if (threadIdx.x == 0){ sum[bi] = rs[0]; sumsq[bi] = rss[0]; }
}

// inorm(1e-3) + bnorm(1e-5) collapse: per (b,i) m and combined scale s
__global__ void k_xscale(const float* __restrict__ sum, const float* __restrict__ sumsq,
                         float* __restrict__ mOut, float* __restrict__ sOut){
  int i = threadIdx.x;                       // channel 0..255
  float vl[NB], ml[NB];
  float V = 0.f;
  for (int b = 0; b < NB; b++){
    int bi = b*CIx + i;
    float m = sum[bi] * (1.f/(float)NKx);
    float v = sumsq[bi] * (1.f/(float)NKx) - m*m;
    ml[b] = m; vl[b] = v;
    V += v / (v + 1e-3f);
  }
  V *= (1.f/(float)NB);
  float bs = rsqrtf(V + 1e-5f);
  for (int b = 0; b < NB; b++){
    int bi = b*CIx + i;
    mOut[bi] = ml[b];
    sOut[bi] = rsqrtf(vl[b] + 1e-3f) * bs;
  }
}

// ---- fold wk@w_att1 / wv@w_att1 into Wf[r][i] bf16 (r<128:K, r>=128:V), row-major ----
__global__ void k_prep_kv(const float* __restrict__ w_att1, const float* __restrict__ wk,
                          const float* __restrict__ wv, const float* __restrict__ b_att1,
                          const float* __restrict__ bk, const float* __restrict__ bv,
                          ushort* __restrict__ Wf, float* __restrict__ bKV){
  int r = blockIdx.x;   // 0..255
  int i = threadIdx.x;  // 0..255
  const float* wr = (r < 128) ? (wk + r*128) : (wv + (r-128)*128);
  float acc = 0.f;
  for (int c = 0; c < 128; c++) acc += wr[c] * w_att1[c*CIx + i];
  Wf[r*256 + i] = f2bf(acc);
  if (i == 0){
    float bacc = (r < 128) ? bk[r] : bv[r-128];
    for (int c = 0; c < 128; c++) bacc += wr[c] * b_att1[c];
    bKV[r] = bacc;
  }
}

// ---- pack conv weights to bf16 [r][i] + stacked bias2 ----
__global__ void k_prepW(const float* __restrict__ wq, const float* __restrict__ w_right,
                        const float* __restrict__ w_l1, const float* __restrict__ w_l2,
                        const float* __restrict__ w_l3, const float* __restrict__ b_right,
                        const float* __restrict__ b_l1,
                        ushort* __restrict__ Wq, ushort* __restrict__ W2,
                        ushort* __restrict__ W3, ushort* __restrict__ W4,
                        float* __restrict__ bias2){
  int idx = blockIdx.x*256 + threadIdx.x;
  if (idx < 16384){ Wq[idx] = f2bf(wq[idx]); return; }
  idx -= 16384;
  if (idx < 65536){
    int r = idx >> 8, i = idx & 255;
    W2[idx] = f2bf(r < 128 ? w_right[r*256+i] : w_l1[(r-128)*256+i]);
    return;
  }
  idx -= 65536;
  if (idx < 16384){ W3[idx] = f2bf(w_l2[idx]); return; }
  idx -= 16384;
  if (idx < 16384){ W4[idx] = f2bf(w_l3[idx]); return; }
  idx -= 16384;
  if (idx < 256) bias2[idx] = (idx < 128) ? b_right[idx] : b_l1[idx-128];
}

// ---------------- fused MFMA attention + q-conv, 8-n tile ----------------
// D[colx][r] = sum_i relu((x[i][col]-m_i)*s_i) * Wf[r][i]   (C^T orientation)
// Staging restructured to 8i x 4col tasks -> 4x ds_write_b128 (wide LDS writes).
__global__ __launch_bounds__(256,3) void k_attn_mfma(
    const float* __restrict__ xl, const float* __restrict__ x_row,
    const float* __restrict__ mArr, const float* __restrict__ sArr,
    const ushort* __restrict__ Wf, const float* __restrict__ bKV,
    const ushort* __restrict__ Wq, const float* __restrict__ bq,
    float* __restrict__ out_local)
{
  const int b   = blockIdx.y;
  const int n0  = blockIdx.x * 8;
  const int col0 = n0 * KW;                 // 72 * blockIdx.x
  const int tid = threadIdx.x;
  const int w   = tid >> 6;
  const int lane = tid & 63;
  const int c16 = lane & 15, g = lane >> 4;

  __shared__ ushort wlds[20480];            // 40960B: frag staging; aliased after main loop
  __shared__ ushort qlds[2048];             // 4096B: x_row frags for q-GEMM
  __shared__ float  qbuf[128*8];            // 4096B: q exchange
  ushort (*elds)[16][72] = (ushort (*)[16][72])wlds;   // 36864B: [w*4+j][c16][col]
  float* obuf = (float*)(wlds + 18432);     // last 4096B of wlds: [128][8] out buffer

  // zero the pad region (mt=4, cj 8..15) once
  {
    unsigned* fb = (unsigned*)wlds;
#pragma unroll
    for (int zz = 0; zz < 4; zz++){
      int z = tid + 256*zz;                 // 0..1023
      int io2 = z & 3, cj = 8 + ((z>>2)&7), g_ = (z>>5)&3, s = z>>7;
      fb[((s*5 + 4)*4 + g_)*64 + pi16(cj,4)*4 + io2] = 0u;
    }
  }

  // ---- stage x_row[128][8] -> qlds frags (bf16); zero cols 8..15 ----
  {
    int row = tid >> 1, half = tid & 1;
    const float* xr = x_row + ((size_t)(b*COx + row))*NPTS + n0 + 4*half;
    float4 v = *(const float4*)xr;
    int kq = row >> 5, g_ = (row >> 3) & 3, io = row & 7;
    int base = (kq*4 + g_)*128 + io;        // + cj*8
    float a[4] = {v.x, v.y, v.z, v.w};
#pragma unroll
    for (int j = 0; j < 4; j++){
      qlds[base + (4*half + j)*8] = f2bf(a[j]);
      qlds[base + (8 + 4*half + j)*8] = 0;
    }
  }

  // ---- stage 256 i x 72 cols: 8i x 4col tasks, b128 LDS writes ----
  {
    const size_t xb = (size_t)b*CIx*NKx + col0;
    const float* mB = mArr + b*CIx;
    const float* sB = sArr + b*CIx;
#pragma unroll
    for (int kk = 0; kk < 3; kk++){
      int idx = tid + 256*kk;               // 0..575 = 32 i-groups x 18 col4-groups
      if (idx < 576){
        int ig  = idx / 18;
        int c4g = idx - 18*ig;
        int i0  = ig*8;
        int s = ig >> 2, g_ = ig & 3;
        int mt = c4g >> 2;
        int cb4 = 4*(c4g & 3);              // cjl base within 16
        float4 m4a = *(const float4*)(mB + i0);
        float4 m4b = *(const float4*)(mB + i0 + 4);
        float4 s4a = *(const float4*)(sB + i0);
        float4 s4b = *(const float4*)(sB + i0 + 4);
        float mr[8] = {m4a.x,m4a.y,m4a.z,m4a.w,m4b.x,m4b.y,m4b.z,m4b.w};
        float sr[8] = {s4a.x,s4a.y,s4a.z,s4a.w,s4b.x,s4b.y,s4b.z,s4b.w};
        float xvv[8][4];
#pragma unroll
        for (int r = 0; r < 8; r++)
          *(float4*)&xvv[r][0] = *(const float4*)(xl + xb + (size_t)(i0+r)*NKx + 4*c4g);
        unsigned* slotbase = (unsigned*)wlds + ((s*5 + mt)*4 + g_)*64;
#pragma unroll
        for (int j = 0; j < 4; j++){
          u32x4 w4;
#pragma unroll
          for (int io2 = 0; io2 < 4; io2++){
            float v0 = fmaxf((xvv[2*io2][j]   - mr[2*io2])   * sr[2*io2],   0.f);
            float v1 = fmaxf((xvv[2*io2+1][j] - mr[2*io2+1]) * sr[2*io2+1], 0.f);
            w4[io2] = (unsigned)f2bf(v0) | ((unsigned)f2bf(v1) << 16);
          }
          *(u32x4*)(slotbase + pi16(cb4 + j, mt)*4) = w4;
        }
      }
    }
  }
  __syncthreads();

  // ---- accumulators init AFTER staging ----
  f32x4 acc[5][4];
#pragma unroll
  for (int mt = 0; mt < 5; mt++)
#pragma unroll
    for (int j = 0; j < 4; j++) acc[mt][j] = (f32x4)0.f;

  // ---- 8 K-steps, 160 MFMAs, no barriers ----
  {
    const int ct0 = w, ct1 = w + 4, ct2 = w + 8, ct3 = w + 12;
#pragma unroll
    for (int s = 0; s < 8; s++){
      bf16x8 wf0 = *(const bf16x8*)(Wf + (ct0*16 + c16)*256 + s*32 + g*8);
      bf16x8 wf1 = *(const bf16x8*)(Wf + (ct1*16 + c16)*256 + s*32 + g*8);
      bf16x8 wf2 = *(const bf16x8*)(Wf + (ct2*16 + c16)*256 + s*32 + g*8);
      bf16x8 wf3 = *(const bf16x8*)(Wf + (ct3*16 + c16)*256 + s*32 + g*8);
#pragma unroll
      for (int mt = 0; mt < 5; mt++){
        bf16x8 af = *(const bf16x8*)(wlds + ((s*5 + mt)*4 + g)*128 + pi16(c16, mt)*8);
        acc[mt][0] = __builtin_amdgcn_mfma_f32_16x16x32_bf16(af, wf0, acc[mt][0], 0,0,0);
        acc[mt][1] = __builtin_amdgcn_mfma_f32_16x16x32_bf16(af, wf1, acc[mt][1], 0,0,0);
        acc[mt][2] = __builtin_amdgcn_mfma_f32_16x16x32_bf16(af, wf2, acc[mt][2], 0,0,0);
        acc[mt][3] = __builtin_amdgcn_mfma_f32_16x16x32_bf16(af, wf3, acc[mt][3], 0,0,0);
      }
    }
  }

  // ---- q-GEMM: 8 MFMAs/wave, channels chA (j=0) and chA+64 (j=1) ----
  f32x4 accq[2];
  accq[0] = (f32x4)0.f; accq[1] = (f32x4)0.f;
  {
#pragma unroll
    for (int kq = 0; kq < 4; kq++){
      bf16x8 afq = *(const bf16x8*)(qlds + (kq*4 + g)*128 + c16*8);
      bf16x8 wq0 = *(const bf16x8*)(Wq + ((w     )*16 + c16)*128 + kq*32 + g*8);
      bf16x8 wq1 = *(const bf16x8*)(Wq + ((w + 4 )*16 + c16)*128 + kq*32 + g*8);
      accq[0] = __builtin_amdgcn_mfma_f32_16x16x32_bf16(afq, wq0, accq[0], 0,0,0);
      accq[1] = __builtin_amdgcn_mfma_f32_16x16x32_bf16(afq, wq1, accq[1], 0,0,0);
    }
  }
  __syncthreads();    // staging dead; elds/obuf alias wlds from here

  const int chA = w*16 + c16;

  // ---- qbuf write (float4) + elds dump (8B writes), single barrier ----
  if (g < 2){
#pragma unroll
    for (int j = 0; j < 2; j++){
      int ch = chA + 64*j;
      float bb = bq[ch];
      float4 qv;
      qv.x = accq[j][0] + bb; qv.y = accq[j][1] + bb;
      qv.z = accq[j][2] + bb; qv.w = accq[j][3] + bb;
      *(float4*)&qbuf[ch*8 + 4*g] = qv;
    }
  }
#pragma unroll
  for (int mt = 0; mt < 5; mt++){
    if (mt < 4 || g < 2){
      int colb = 16*mt + 4*g;
#pragma unroll
      for (int j = 0; j < 4; j++){
        u32x2 w2;
        w2[0] = (unsigned)f2bf(acc[mt][j][0]) | ((unsigned)f2bf(acc[mt][j][1]) << 16);
        w2[1] = (unsigned)f2bf(acc[mt][j][2]) | ((unsigned)f2bf(acc[mt][j][3]) << 16);
        *(u32x2*)&elds[w*4 + j][c16][colb] = w2;
      }
    }
  }
  __syncthreads();

  float bk0 = bKV[chA], bk1 = bKV[chA + 64];
  float bv0 = bKV[128 + chA], bv1 = bKV[128 + chA + 64];

  // ---- softmax over K=9 + PV, both ch halves ----
#pragma unroll
  for (int h = 0; h < 2; h++){
    float bk_ = h ? bk1 : bk0;
    float bv_ = h ? bv1 : bv0;
    int ch = chA + 64*h;
    const ushort* eK = &elds[w*4 + h][c16][0];
    const ushort* eV = &elds[w*4 + 2 + h][c16][0];
    float o2[2];
#pragma unroll
    for (int t = 0; t < 2; t++){
      int nloc = 2*g + t;
      int cb = 9*nloc;
      float qq = qbuf[ch*8 + nloc];
      float sc[KW];
      float mx = -1e30f;
#pragma unroll
      for (int k = 0; k < KW; k++){
        float s_ = qq * (bf2f(eK[cb + k]) + bk_);
        sc[k] = s_;
        mx = fmaxf(mx, s_);
      }
      float den = 0.f, num = 0.f;
#pragma unroll
      for (int k = 0; k < KW; k++){
        float e = __expf(sc[k] - mx);
        den += e;
        num += e * (bf2f(eV[cb + k]) + bv_);
      }
      o2[t] = num / den;
    }
    *(float2*)&obuf[ch*8 + 2*g] = make_float2(o2[0], o2[1]);
  }
  __syncthreads();

  // ---- coalesced store: 2 threads per channel ----
  {
    int ch = tid >> 1, part = tid & 1;
    float4 v = *(float4*)&obuf[ch*8 + 4*part];
    *(float4*)(out_local + ((size_t)(b*COx + ch))*NPTS + n0 + 4*part) = v;
  }
}

// ---------------- generic MFMA conv1x1 over n-tiles of 80 ----------------
// MODE 1: conv2x + stats(c1); MODE 2: c2 (+uout, stats); MODE 3: c3 (stats)
template<int MODE>
__global__ __launch_bounds__(256) void k_mconv(
    const float* __restrict__ inA, const float* __restrict__ inB,
    const ushort* __restrict__ Wc, const float* __restrict__ bias,
    const float* __restrict__ nm, const float* __restrict__ nsc,
    float* __restrict__ out0, float* __restrict__ out1,
    float* __restrict__ uout, float* __restrict__ pstat)
{
  constexpr int IC = (MODE==1) ? 256 : 128;
  constexpr int RC = (MODE==1) ? 256 : 128;
  constexpr int NS = IC/32;
  constexpr int JW = RC/64;
  constexpr int PHASES = RC/128;
  constexpr bool STATS = (MODE >= 1);
  constexpr int SPH = (MODE==1) ? 1 : 0;

  const int b = blockIdx.y, bx = blockIdx.x;
  const int n0 = bx*80;
  const int tid = threadIdx.x;
  const int w = tid>>6, lane = tid&63;
  const int c16 = lane&15, g = lane>>4;

  __shared__ ushort smem[21504];

  {
    constexpr int TOT = (IC/2)*20;
    const float* srcA = inA + (size_t)b*128*NPTS;
    const float* srcB = inB ? (inB + (size_t)b*128*NPTS) : nullptr;
    for (int idx = tid; idx < TOT; idx += 256){
      int pr = idx/20, c4 = idx - 20*pr;
      int i = pr*2;
      int cc = n0 + 4*c4;
      float4 va, vb;
      if (MODE == 1){
        const float* base = (i < 128) ? (srcA + (size_t)i*NPTS + cc)
                                      : (srcB + (size_t)(i-128)*NPTS + cc);
        va = *(const float4*)base;
        vb = *(const float4*)(base + NPTS);
      } else {
        const float* pa = srcA + (size_t)i*NPTS + cc;
        const float* pb = srcB + (size_t)i*NPTS + cc;
        float4 ca = *(const float4*)pa, cb = *(const float4*)(pa+NPTS);
        float4 aa = *(const float4*)pb, ab = *(const float4*)(pb+NPTS);
        float m0 = nm[b*128+i],   s0 = nsc[b*128+i];
        float m1 = nm[b*128+i+1], s1 = nsc[b*128+i+1];
        va.x = fmaxf((ca.x-m0)*s0,0.f)+aa.x; va.y = fmaxf((ca.y-m0)*s0,0.f)+aa.y;
        va.z = fmaxf((ca.z-m0)*s0,0.f)+aa.z; va.w = fmaxf((ca.w-m0)*s0,0.f)+aa.w;
        vb.x = fmaxf((cb.x-m1)*s1,0.f)+ab.x; vb.y = fmaxf((cb.y-m1)*s1,0.f)+ab.y;
        vb.z = fmaxf((cb.z-m1)*s1,0.f)+ab.z; vb.w = fmaxf((cb.w-m1)*s1,0.f)+ab.w;
        if (MODE == 2){
          float4 u0, u1;
          u0.x = va.x+aa.x; u0.y = va.y+aa.y; u0.z = va.z+aa.z; u0.w = va.w+aa.w;
          u1.x = vb.x+ab.x; u1.y = vb.y+ab.y; u1.z = vb.z+ab.z; u1.w = vb.w+ab.w;
          *(float4*)(uout + ((size_t)(b*128+i))*NPTS + cc) = u0;
          *(float4*)(uout + ((size_t)(b*128+i+1))*NPTS + cc) = u1;
        }
      }
      int sp = i>>5, g_ = (i>>3)&3, io2 = (i>>1)&3;
      int mt = c4>>2;
      unsigned* dstb = (unsigned*)smem + ((sp*5 + mt)*4 + g_)*64 + io2;
      float a0[4] = {va.x, va.y, va.z, va.w};
      float a1[4] = {vb.x, vb.y, vb.z, vb.w};
#pragma unroll
      for (int j = 0; j < 4; j++){
        int cj = (4*c4 + j) & 15;
        int pi = pi16(cj, mt);
        dstb[pi*4] = (unsigned)f2bf(a0[j]) | ((unsigned)f2bf(a1[j]) << 16);
      }
    }
  }
  __syncthreads();

  f32x4 acc[5][JW];
#pragma unroll
  for (int mt = 0; mt < 5; mt++)
#pragma unroll
    for (int j = 0; j < JW; j++) acc[mt][j] = (f32x4)0.f;

  for (int s = 0; s < NS; s++){
    bf16x8 wf[JW];
#pragma unroll
    for (int j = 0; j < JW; j++)
      wf[j] = *(const bf16x8*)(Wc + ((w + 4*j)*16 + c16)*IC + s*32 + g*8);
#pragma unroll
    for (int mt = 0; mt < 5; mt++){
      bf16x8 af = *(const bf16x8*)(smem + ((s*5 + mt)*4 + g)*128 + pi16(c16, mt)*8);
#pragma unroll
      for (int j = 0; j < JW; j++)
        acc[mt][j] = __builtin_amdgcn_mfma_f32_16x16x32_bf16(af, wf[j], acc[mt][j], 0,0,0);
    }
  }

  float* dl = (float*)smem;
#pragma unroll
  for (int ph = 0; ph < PHASES; ph++){
    __syncthreads();
    float st_s[2], st_ss[2];
#pragma unroll
    for (int jj = 0; jj < 2; jj++){
      int j = ph*2 + jj;
      int ct = w + 4*j;
      int rl = (ct & 7)*16 + c16;
      float bb = bias[ct*16 + c16];
      float s = 0.f, ss = 0.f;
#pragma unroll
      for (int mt = 0; mt < 5; mt++){
        f32x4 v = acc[mt][j];
        float4 vv;
        vv.x = v[0]+bb; vv.y = v[1]+bb; vv.z = v[2]+bb; vv.w = v[3]+bb;
        *(float4*)&dl[rl*84 + mt*16 + 4*g] = vv;
        s  += vv.x + vv.y + vv.z + vv.w;
        ss += vv.x*vv.x + vv.y*vv.y + vv.z*vv.z + vv.w*vv.w;
      }
      st_s[jj] = s; st_ss[jj] = ss;
    }
    if (STATS && ph == SPH){
#pragma unroll
      for (int jj = 0; jj < 2; jj++){
        float s = st_s[jj], ss = st_ss[jj];
        s += __shfl_xor(s, 16); ss += __shfl_xor(ss, 16);
        s += __shfl_xor(s, 32); ss += __shfl_xor(ss, 32);
        if (g == 0){
          int ct = w + 4*(ph*2 + jj);
          int rl = (ct & 7)*16 + c16;
          int off = (b*NTIL + bx)*128 + rl;
          pstat[off]           = s;
          pstat[PSTRIDE + off] = ss;
        }
      }
    }
    __syncthreads();
    float* dst = ph ? out1 : out0;
#pragma unroll
    for (int kk = 0; kk < 10; kk++){
      int idx = kk*256 + tid;
      int r = idx/20, c4 = idx - 20*r;
      *(float4*)(dst + ((size_t)(b*128 + r))*NPTS + n0 + 4*c4) = *(float4*)&dl[r*84 + 4*c4];
    }
  }
}

// ---- reduce pstat -> per-(b,c) m and combined inorm(1e-5)+bnorm scale (parallel) ----
__global__ __launch_bounds__(1024) void k_red(const float* __restrict__ pstat,
                                              float* __restrict__ cm, float* __restrict__ cs){
  __shared__ float msh[2048], vsh[2048], wsh[2048];
  int t = threadIdx.x;
#pragma unroll
  for (int h = 0; h < 2; h++){
    int p = t + h*1024;
    int b = p >> 7, c = p & 127;
    float s = 0.f, ss = 0.f;
    for (int tt = 0; tt < NTIL; tt++){
      int off = (b*NTIL + tt)*128 + c;
      s  += pstat[off];
      ss += pstat[PSTRIDE + off];
    }
    float m = s * (1.f/(float)NPTS);
    float v = ss * (1.f/(float)NPTS) - m*m;
    msh[p] = m; vsh[p] = v; wsh[p] = v/(v + 1e-5f);
  }
  __syncthreads();
  if (t < 128){
    float V = 0.f;
    for (int b = 0; b < NB; b++) V += wsh[b*128 + t];
    float bs = rsqrtf(V*(1.f/(float)NB) + 1e-5f);
    for (int b = 0; b < NB; b++){
      cm[b*COx + t] = msh[b*128 + t];
      cs[b*COx + t] = rsqrtf(vsh[b*128 + t] + 1e-5f) * bs;
    }
  }
}

// o3 = relu(norm(c3)+x1); t = x_row + g*o3; out = 0.5*(t + mean_c t)
__global__ __launch_bounds__(256) void k_final(const float* __restrict__ c3, const float* __restrict__ x1,
    const float* __restrict__ x_row, const float* __restrict__ cm, const float* __restrict__ cs,
    const float* __restrict__ gamma1, float* __restrict__ out)
{
  const int b  = blockIdx.y;
  const int n0 = blockIdx.x * 50;
  const int tid = threadIdx.x;
  const float g = gamma1[0];
  __shared__ float tt[128][50];
  __shared__ float part[4][50];
  for (int idx = tid; idx < 128*50; idx += 256){
    int c = idx / 50; int j = idx - c*50;
    size_t off = ((size_t)b*COx + c)*NPTS + n0 + j;
    float o3 = fmaxf((c3[off] - cm[b*COx + c]) * cs[b*COx + c] + x1[off], 0.f);
    tt[c][j] = x_row[off] + g * o3;
  }
  __syncthreads();
  if (tid < 200){
    int gg = tid / 50, j = tid - gg*50;
    float s = 0.f;
    for (int c = gg*32; c < gg*32 + 32; c++) s += tt[c][j];
    part[gg][j] = s;
  }
  __syncthreads();
  for (int idx = tid; idx < 128*50; idx += 256){
    int c = idx / 50; int j = idx - c*50;
    float mean = (part[0][j] + part[1][j] + part[2][j] + part[3][j]) * (1.f/128.f);
    out[((size_t)b*COx + c)*NPTS + n0 + j] = 0.5f * (tt[c][j] + mean);
  }
}

extern "C" void kernel_launch(void* const* d_in, const int* in_sizes, int n_in,
                              void* d_out, int out_size, void* d_ws, size_t ws_size,
                              hipStream_t stream){
  (void)in_sizes; (void)n_in; (void)out_size; (void)ws_size;
  const float* x_row   = (const float*)d_in[0];
  const float* x_local = (const float*)d_in[1];
  const float* w_att1  = (const float*)d_in[2];
  const float* b_att1  = (const float*)d_in[3];
  const float* wq      = (const float*)d_in[4];
  const float* bq      = (const float*)d_in[5];
  const float* wk      = (const float*)d_in[6];
  const float* bk      = (const float*)d_in[7];
  const float* wv      = (const float*)d_in[8];
  const float* bv      = (const float*)d_in[9];
  const float* w_right = (const float*)d_in[10];
  const float* b_right = (const float*)d_in[11];
  const float* w_l1    = (const float*)d_in[12];
  const float* b_l1    = (const float*)d_in[13];
  const float* w_l2    = (const float*)d_in[14];
  const float* b_l2    = (const float*)d_in[15];
  const float* w_l3    = (const float*)d_in[16];
  const float* b_l3    = (const float*)d_in[17];
  const float* gamma1  = (const float*)d_in[18];
  float* out = (float*)d_out;

  float*  ws     = (float*)d_ws;
  float*  sum    = ws;                        // 4096
  float*  sumsq  = ws + 4096;                 // 4096
  float*  mArr   = ws + 8192;                 // 4096
  float*  sArr   = ws + 12288;                // 4096
  ushort* Wf     = (ushort*)(ws + 16384);     // 65536 us = 32768 floats
  float*  bKV    = ws + 49152;                // 256
  ushort* Wq     = (ushort*)(ws + 49408);     // 16384 us
  ushort* W2     = (ushort*)(ws + 57600);     // 65536 us
  ushort* W3     = (ushort*)(ws + 90368);     // 16384 us
  ushort* W4     = (ushort*)(ws + 98560);     // 16384 us
  float*  bias2  = ws + 106752;               // 256
  float*  cm     = ws + 107008;               // 2048
  float*  cs     = ws + 109056;               // 2048
  float*  pstat  = ws + 111104;               // 102400 (s plane + ss plane)
  float*  P0 = ws + 262144;                   // 4,096,000 each
  float*  P1 = P0 + 4096000;
  float*  P2 = P1 + 4096000;
  float*  P3 = P2 + 4096000;

  // stats + weight prep
  k_xstats <<<4096, 256, 0, stream>>>(x_local, sum, sumsq);
  k_xscale <<<1, 256, 0, stream>>>(sum, sumsq, mArr, sArr);
  k_prep_kv<<<256, 256, 0, stream>>>(w_att1, wk, wv, b_att1, bk, bv, Wf, bKV);
  k_prepW  <<<450, 256, 0, stream>>>(wq, w_right, w_l1, w_l2, w_l3, b_right, b_l1,
                                     Wq, W2, W3, W4, bias2);

  // fused MFMA attention (q computed in-kernel) -> out_local (P0)
  k_attn_mfma<<<dim3(250, NB), 256, 0, stream>>>(x_local, x_row, mArr, sArr, Wf, bKV, Wq, bq, P0);

  // x1 (P1), c1 (P2) + stats(c1)
  k_mconv<1><<<dim3(NTIL, NB), 256, 0, stream>>>(x_row, P0, W2, bias2,
                                                 nullptr, nullptr, P1, P2, nullptr, pstat);
  k_red<<<1, 1024, 0, stream>>>(pstat, cm, cs);

  // stage o1 = relu(norm(c1))+x1; c2 (P3); u = o1+x1 -> P0; stats(c2)
  k_mconv<2><<<dim3(NTIL, NB), 256, 0, stream>>>(P2, P1, W3, b_l2,
                                                 cm, cs, P3, nullptr, P0, pstat);
  k_red<<<1, 1024, 0, stream>>>(pstat, cm, cs);

  // stage o2 = relu(norm(c2))+u; c3 (P2); stats(c3)
  k_mconv<3><<<dim3(NTIL, NB), 256, 0, stream>>>(P3, P0, W4, b_l3,
                                                 cm, cs, P2, nullptr, nullptr, pstat);
  k_red<<<1, 1024, 0, stream>>>(pstat, cm, cs);

  // final
  k_final<<<dim3(NPTS/50, NB), 256, 0, stream>>>(P2, P1, x_row, cm, cs, gamma1, out);
}

// Round 15
// 301.501 us; speedup vs baseline: 1.0510x; 1.0038x over previous
//
#include <hip/hip_runtime.h>
#include <math.h>

#define NB    16
#define CIx   256
#define COx   128
#define NPTS  2000
#define KW    9
#define NKx   18000   // NPTS*KW
#define NTIL  25      // n tiles of 80 for mconv
#define PSTRIDE 51200 // NB*NTIL*128

typedef short bf16x8 __attribute__((ext_vector_type(8)));
typedef float f32x4  __attribute__((ext_vector_type(4)));
typedef unsigned int u32x4 __attribute__((ext_vector_type(4)));
typedef unsigned int u32x2 __attribute__((ext_vector_type(2)));

__device__ __forceinline__ ushort f2bf(float f){
  unsigned u = __builtin_bit_cast(unsigned, f);
  u = (u + 0x7fffu + ((u>>16)&1u)) >> 16;
  return (ushort)u;
}
__device__ __forceinline__ float bf2f(ushort h){
  unsigned u = ((unsigned)h)<<16;
  return __builtin_bit_cast(float, u);
}
// per-mt within-slot placement permutation: bijective, puts mt parity into bank bit 4
__device__ __forceinline__ int pi16(int c, int mt){
  return (((c & 3) ^ (mt & 3)) << 2) | (c >> 2);
}

// ---------------- stats over x_local: per (b,i) sum/sumsq over 18000 ----------------
__global__ __launch_bounds__(256) void k_xstats(const float* __restrict__ xl,
    float* __restrict__ sum, float* __restrict__ sumsq){
  int bi = blockIdx.x;                       // b*256 + i
  const float4* p = (const float4*)(xl + (size_t)bi * NKx);
  float s = 0.f, ss = 0.f;
  for (int idx = threadIdx.x; idx < NKx/4; idx += 256){
    float4 v = p[idx];
    s  += v.x + v.y + v.z + v.w;
    ss += v.x*v.x + v.y*v.y + v.z*v.z + v.w*v.w;
  }
  __shared__ float rs[256], rss[256];
  rs[threadIdx.x] = s; rss[threadIdx.x] = ss;
  __syncthreads();
  for (int off = 128; off > 0; off >>= 1){
    if (threadIdx.x < off){ rs[threadIdx.x] += rs[threadIdx.x+off]; rss[threadIdx.x] += rss[threadIdx.x+off]; }
    __syncthreads();
  }
  if (threadIdx.x == 0){ sum[bi] = rs[0]; sumsq[bi] = rss[0]; }
}

// inorm(1e-3) + bnorm(1e-5) collapse: per (b,i) m and combined scale s
__global__ void k_xscale(const float* __restrict__ sum, const float* __restrict__ sumsq,
                         float* __restrict__ mOut, float* __restrict__ sOut){
  int i = threadIdx.x;                       // channel 0..255
  float vl[NB], ml[NB];
  float V = 0.f;
  for (int b = 0; b < NB; b++){
    int bi = b*CIx + i;
    float m = sum[bi] * (1.f/(float)NKx);
    float v = sumsq[bi] * (1.f/(float)NKx) - m*m;
    ml[b] = m; vl[b] = v;
    V += v / (v + 1e-3f);
  }
  V *= (1.f/(float)NB);
  float bs = rsqrtf(V + 1e-5f);
  for (int b = 0; b < NB; b++){
    int bi = b*CIx + i;
    mOut[bi] = ml[b];
    sOut[bi] = rsqrtf(vl[b] + 1e-3f) * bs;
  }
}

// ---- fold wk@w_att1 / wv@w_att1 into Wf[r][i] bf16 (r<128:K, r>=128:V), row-major ----
__global__ void k_prep_kv(const float* __restrict__ w_att1, const float* __restrict__ wk,
                          const float* __restrict__ wv, const float* __restrict__ b_att1,
                          const float* __restrict__ bk, const float* __restrict__ bv,
                          ushort* __restrict__ Wf, float* __restrict__ bKV){
  int r = blockIdx.x;   // 0..255
  int i = threadIdx.x;  // 0..255
  const float* wr = (r < 128) ? (wk + r*128) : (wv + (r-128)*128);
  float acc = 0.f;
  for (int c = 0; c < 128; c++) acc += wr[c] * w_att1[c*CIx + i];
  Wf[r*256 + i] = f2bf(acc);
  if (i == 0){
    float bacc = (r < 128) ? bk[r] : bv[r-128];
    for (int c = 0; c < 128; c++) bacc += wr[c] * b_att1[c];
    bKV[r] = bacc;
  }
}

// ---- pack conv weights to bf16 [r][i] + stacked bias2 ----
__global__ void k_prepW(const float* __restrict__ wq, const float* __restrict__ w_right,
                        const float* __restrict__ w_l1, const float* __restrict__ w_l2,
                        const float* __restrict__ w_l3, const float* __restrict__ b_right,
                        const float* __restrict__ b_l1,
                        ushort* __restrict__ Wq, ushort* __restrict__ W2,
                        ushort* __restrict__ W3, ushort* __restrict__ W4,
                        float* __restrict__ bias2){
  int idx = blockIdx.x*256 + threadIdx.x;
  if (idx < 16384){ Wq[idx] = f2bf(wq[idx]); return; }
  idx -= 16384;
  if (idx < 65536){
    int r = idx >> 8, i = idx & 255;
    W2[idx] = f2bf(r < 128 ? w_right[r*256+i] : w_l1[(r-128)*256+i]);
    return;
  }
  idx -= 65536;
  if (idx < 16384){ W3[idx] = f2bf(w_l2[idx]); return; }
  idx -= 16384;
  if (idx < 16384){ W4[idx] = f2bf(w_l3[idx]); return; }
  idx -= 16384;
  if (idx < 256) bias2[idx] = (idx < 128) ? b_right[idx] : b_l1[idx-128];
}

// ---------------- fused MFMA attention + q-conv, 8-n tile ----------------
// D[colx][r] = sum_i relu((x[i][col]-m_i)*s_i) * Wf[r][i]   (C^T orientation)
// Staging: 8i x 4col tasks -> 4x ds_write_b128 (wide LDS writes).
__global__ __launch_bounds__(256,3) void k_attn_mfma(
    const float* __restrict__ xl, const float* __restrict__ x_row,
    const float* __restrict__ mArr, const float* __restrict__ sArr,
    const ushort* __restrict__ Wf, const float* __restrict__ bKV,
    const ushort* __restrict__ Wq, const float* __restrict__ bq,
    float* __restrict__ out_local)
{
  const int b   = blockIdx.y;
  const int n0  = blockIdx.x * 8;
  const int col0 = n0 * KW;                 // 72 * blockIdx.x
  const int tid = threadIdx.x;
  const int w   = tid >> 6;
  const int lane = tid & 63;
  const int c16 = lane & 15, g = lane >> 4;

  __shared__ ushort wlds[20480];            // 40960B: frag staging; aliased after main loop
  __shared__ ushort qlds[2048];             // 4096B: x_row frags for q-GEMM
  __shared__ float  qbuf[128*8];            // 4096B: q exchange
  ushort (*elds)[16][72] = (ushort (*)[16][72])wlds;   // 36864B: [w*4+j][c16][col]
  float* obuf = (float*)(wlds + 18432);     // last 4096B of wlds: [128][8] out buffer

  // zero the pad region (mt=4, cj 8..15) once
  {
    unsigned* fb = (unsigned*)wlds;
#pragma unroll
    for (int zz = 0; zz < 4; zz++){
      int z = tid + 256*zz;                 // 0..1023
      int io2 = z & 3, cj = 8 + ((z>>2)&7), g_ = (z>>5)&3, s = z>>7;
      fb[((s*5 + 4)*4 + g_)*64 + pi16(cj,4)*4 + io2] = 0u;
    }
  }

  // ---- stage x_row[128][8] -> qlds frags (bf16); zero cols 8..15 ----
  {
    int row = tid >> 1, half = tid & 1;
    const float* xr = x_row + ((size_t)(b*COx + row))*NPTS + n0 + 4*half;
    float4 v = *(const float4*)xr;
    int kq = row >> 5, g_ = (row >> 3) & 3, io = row & 7;
    int base = (kq*4 + g_)*128 + io;        // + cj*8
    float a[4] = {v.x, v.y, v.z, v.w};
#pragma unroll
    for (int j = 0; j < 4; j++){
      qlds[base + (4*half + j)*8] = f2bf(a[j]);
      qlds[base + (8 + 4*half + j)*8] = 0;
    }
  }

  // ---- stage 256 i x 72 cols: 8i x 4col tasks, b128 LDS writes ----
  {
    const size_t xb = (size_t)b*CIx*NKx + col0;
    const float* mB = mArr + b*CIx;
    const float* sB = sArr + b*CIx;
#pragma unroll
    for (int kk = 0; kk < 3; kk++){
      int idx = tid + 256*kk;               // 0..575 = 32 i-groups x 18 col4-groups
      if (idx < 576){
        int ig  = idx / 18;
        int c4g = idx - 18*ig;
        int i0  = ig*8;
        int s = ig >> 2, g_ = ig & 3;
        int mt = c4g >> 2;
        int cb4 = 4*(c4g & 3);              // cjl base within 16
        float4 m4a = *(const float4*)(mB + i0);
        float4 m4b = *(const float4*)(mB + i0 + 4);
        float4 s4a = *(const float4*)(sB + i0);
        float4 s4b = *(const float4*)(sB + i0 + 4);
        float mr[8] = {m4a.x,m4a.y,m4a.z,m4a.w,m4b.x,m4b.y,m4b.z,m4b.w};
        float sr[8] = {s4a.x,s4a.y,s4a.z,s4a.w,s4b.x,s4b.y,s4b.z,s4b.w};
        float xvv[8][4];
#pragma unroll
        for (int r = 0; r < 8; r++)
          *(float4*)&xvv[r][0] = *(const float4*)(xl + xb + (size_t)(i0+r)*NKx + 4*c4g);
        unsigned* slotbase = (unsigned*)wlds + ((s*5 + mt)*4 + g_)*64;
#pragma unroll
        for (int j = 0; j < 4; j++){
          u32x4 w4;
#pragma unroll
          for (int io2 = 0; io2 < 4; io2++){
            float v0 = fmaxf((xvv[2*io2][j]   - mr[2*io2])   * sr[2*io2],   0.f);
            float v1 = fmaxf((xvv[2*io2+1][j] - mr[2*io2+1]) * sr[2*io2+1], 0.f);
            w4[io2] = (unsigned)f2bf(v0) | ((unsigned)f2bf(v1) << 16);
          }
          *(u32x4*)(slotbase + pi16(cb4 + j, mt)*4) = w4;
        }
      }
    }
  }
  __syncthreads();

  // ---- accumulators init AFTER staging ----
  f32x4 acc[5][4];
#pragma unroll
  for (int mt = 0; mt < 5; mt++)
#pragma unroll
    for (int j = 0; j < 4; j++) acc[mt][j] = (f32x4)0.f;

  // ---- 8 K-steps, 160 MFMAs, no barriers ----
  {
    const int ct0 = w, ct1 = w + 4, ct2 = w + 8, ct3 = w + 12;
#pragma unroll
    for (int s = 0; s < 8; s++){
      bf16x8 wf0 = *(const bf16x8*)(Wf + (ct0*16 + c16)*256 + s*32 + g*8);
      bf16x8 wf1 = *(const bf16x8*)(Wf + (ct1*16 + c16)*256 + s*32 + g*8);
      bf16x8 wf2 = *(const bf16x8*)(Wf + (ct2*16 + c16)*256 + s*32 + g*8);
      bf16x8 wf3 = *(const bf16x8*)(Wf + (ct3*16 + c16)*256 + s*32 + g*8);
#pragma unroll
      for (int mt = 0; mt < 5; mt++){
        bf16x8 af = *(const bf16x8*)(wlds + ((s*5 + mt)*4 + g)*128 + pi16(c16, mt)*8);
        acc[mt][0] = __builtin_amdgcn_mfma_f32_16x16x32_bf16(af, wf0, acc[mt][0], 0,0,0);
        acc[mt][1] = __builtin_amdgcn_mfma_f32_16x16x32_bf16(af, wf1, acc[mt][1], 0,0,0);
        acc[mt][2] = __builtin_amdgcn_mfma_f32_16x16x32_bf16(af, wf2, acc[mt][2], 0,0,0);
        acc[mt][3] = __builtin_amdgcn_mfma_f32_16x16x32_bf16(af, wf3, acc[mt][3], 0,0,0);
      }
    }
  }

  // ---- q-GEMM: 8 MFMAs/wave, channels chA (j=0) and chA+64 (j=1) ----
  f32x4 accq[2];
  accq[0] = (f32x4)0.f; accq[1] = (f32x4)0.f;
  {
#pragma unroll
    for (int kq = 0; kq < 4; kq++){
      bf16x8 afq = *(const bf16x8*)(qlds + (kq*4 + g)*128 + c16*8);
      bf16x8 wq0 = *(const bf16x8*)(Wq + ((w     )*16 + c16)*128 + kq*32 + g*8);
      bf16x8 wq1 = *(const bf16x8*)(Wq + ((w + 4 )*16 + c16)*128 + kq*32 + g*8);
      accq[0] = __builtin_amdgcn_mfma_f32_16x16x32_bf16(afq, wq0, accq[0], 0,0,0);
      accq[1] = __builtin_amdgcn_mfma_f32_16x16x32_bf16(afq, wq1, accq[1], 0,0,0);
    }
  }
  __syncthreads();    // staging dead; elds/obuf alias wlds from here

  const int chA = w*16 + c16;

  // ---- qbuf write (float4) + elds dump (8B writes), single barrier ----
  if (g < 2){
#pragma unroll
    for (int j = 0; j < 2; j++){
      int ch = chA + 64*j;
      float bb = bq[ch];
      float4 qv;
      qv.x = accq[j][0] + bb; qv.y = accq[j][1] + bb;
      qv.z = accq[j][2] + bb; qv.w = accq[j][3] + bb;
      *(float4*)&qbuf[ch*8 + 4*g] = qv;
    }
  }
#pragma unroll
  for (int mt = 0; mt < 5; mt++){
    if (mt < 4 || g < 2){
      int colb = 16*mt + 4*g;
#pragma unroll
      for (int j = 0; j < 4; j++){
        u32x2 w2;
        w2[0] = (unsigned)f2bf(acc[mt][j][0]) | ((unsigned)f2bf(acc[mt][j][1]) << 16);
        w2[1] = (unsigned)f2bf(acc[mt][j][2]) | ((unsigned)f2bf(acc[mt][j][3]) << 16);
        *(u32x2*)&elds[w*4 + j][c16][colb] = w2;
      }
    }
  }
  __syncthreads();

  float bk0 = bKV[chA], bk1 = bKV[chA + 64];
  float bv0 = bKV[128 + chA], bv1 = bKV[128 + chA + 64];

  // ---- softmax over K=9 + PV, both ch halves ----
#pragma unroll
  for (int h = 0; h < 2; h++){
    float bk_ = h ? bk1 : bk0;
    float bv_ = h ? bv1 : bv0;
    int ch = chA + 64*h;
    const ushort* eK = &elds[w*4 + h][c16][0];
    const ushort* eV = &elds[w*4 + 2 + h][c16][0];
    float o2[2];
#pragma unroll
    for (int t = 0; t < 2; t++){
      int nloc = 2*g + t;
      int cb = 9*nloc;
      float qq = qbuf[ch*8 + nloc];
      float sc[KW];
      float mx = -1e30f;
#pragma unroll
      for (int k = 0; k < KW; k++){
        float s_ = qq * (bf2f(eK[cb + k]) + bk_);
        sc[k] = s_;
        mx = fmaxf(mx, s_);
      }
      float den = 0.f, num = 0.f;
#pragma unroll
      for (int k = 0; k < KW; k++){
        float e = __expf(sc[k] - mx);
        den += e;
        num += e * (bf2f(eV[cb + k]) + bv_);
      }
      o2[t] = num / den;
    }
    *(float2*)&obuf[ch*8 + 2*g] = make_float2(o2[0], o2[1]);
  }
  __syncthreads();

  // ---- coalesced store: 2 threads per channel ----
  {
    int ch = tid >> 1, part = tid & 1;
    float4 v = *(float4*)&obuf[ch*8 + 4*part];
    *(float4*)(out_local + ((size_t)(b*COx + ch))*NPTS + n0 + 4*part) = v;
  }
}

// ---------------- generic MFMA conv1x1 over n-tiles of 80 ----------------
// MODE 1: conv2x + stats(c1); MODE 2: c2 (+uout, stats); MODE 3: c3 (stats)
// Staging: 8i x 4col tasks -> 4x ds_write_b128 (wide LDS writes).
template<int MODE>
__global__ __launch_bounds__(256) void k_mconv(
    const float* __restrict__ inA, const float* __restrict__ inB,
    const ushort* __restrict__ Wc, const float* __restrict__ bias,
    const float* __restrict__ nm, const float* __restrict__ nsc,
    float* __restrict__ out0, float* __restrict__ out1,
    float* __restrict__ uout, float* __restrict__ pstat)
{
  constexpr int IC = (MODE==1) ? 256 : 128;
  constexpr int RC = (MODE==1) ? 256 : 128;
  constexpr int NS = IC/32;
  constexpr int JW = RC/64;
  constexpr int PHASES = RC/128;
  constexpr bool STATS = (MODE >= 1);
  constexpr int SPH = (MODE==1) ? 1 : 0;

  const int b = blockIdx.y, bx = blockIdx.x;
  const int n0 = bx*80;
  const int tid = threadIdx.x;
  const int w = tid>>6, lane = tid&63;
  const int c16 = lane&15, g = lane>>4;

  __shared__ ushort smem[21504];

  // ---- stage input tile [IC][80] -> bf16 frag-linear, b128 LDS writes ----
  {
    constexpr int NT8 = (IC/8)*20;         // 640 (MODE1) or 320
    constexpr int KKN = (NT8 + 255)/256;   // 3 or 2
    const float* srcA = inA + (size_t)b*128*NPTS;
    const float* srcB = inB + (size_t)b*128*NPTS;
#pragma unroll
    for (int kk = 0; kk < KKN; kk++){
      int idx = tid + 256*kk;
      if (idx < NT8){
        int ig = idx / 20, c4 = idx - 20*ig;
        int i0 = ig*8;
        int cc = n0 + 4*c4;
        int sp = i0 >> 5, g_ = (i0 >> 3) & 3;
        int mt = c4 >> 2;
        int cb4 = 4*(c4 & 3);
        float xv[8][4];
        if (MODE == 1){
          const float* src = (i0 < 128) ? (srcA + (size_t)i0*NPTS + cc)
                                        : (srcB + (size_t)(i0-128)*NPTS + cc);
#pragma unroll
          for (int r = 0; r < 8; r++)
            *(float4*)&xv[r][0] = *(const float4*)(src + (size_t)r*NPTS);
        } else {
          float mr[8], sr[8];
          *(float4*)&mr[0] = *(const float4*)(nm + b*128 + i0);
          *(float4*)&mr[4] = *(const float4*)(nm + b*128 + i0 + 4);
          *(float4*)&sr[0] = *(const float4*)(nsc + b*128 + i0);
          *(float4*)&sr[4] = *(const float4*)(nsc + b*128 + i0 + 4);
#pragma unroll
          for (int r = 0; r < 8; r++){
            float4 cv = *(const float4*)(srcA + (size_t)(i0+r)*NPTS + cc);
            float4 av = *(const float4*)(srcB + (size_t)(i0+r)*NPTS + cc);
            xv[r][0] = fmaxf((cv.x - mr[r])*sr[r], 0.f) + av.x;
            xv[r][1] = fmaxf((cv.y - mr[r])*sr[r], 0.f) + av.y;
            xv[r][2] = fmaxf((cv.z - mr[r])*sr[r], 0.f) + av.z;
            xv[r][3] = fmaxf((cv.w - mr[r])*sr[r], 0.f) + av.w;
            if (MODE == 2){
              float4 u4;
              u4.x = xv[r][0] + av.x; u4.y = xv[r][1] + av.y;
              u4.z = xv[r][2] + av.z; u4.w = xv[r][3] + av.w;
              *(float4*)(uout + ((size_t)(b*128 + i0 + r))*NPTS + cc) = u4;
            }
          }
        }
        unsigned* slotbase = (unsigned*)smem + ((sp*5 + mt)*4 + g_)*64;
#pragma unroll
        for (int j = 0; j < 4; j++){
          u32x4 w4;
#pragma unroll
          for (int io2 = 0; io2 < 4; io2++)
            w4[io2] = (unsigned)f2bf(xv[2*io2][j]) | ((unsigned)f2bf(xv[2*io2+1][j]) << 16);
          *(u32x4*)(slotbase + pi16(cb4 + j, mt)*4) = w4;
        }
      }
    }
  }
  __syncthreads();

  f32x4 acc[5][JW];
#pragma unroll
  for (int mt = 0; mt < 5; mt++)
#pragma unroll
    for (int j = 0; j < JW; j++) acc[mt][j] = (f32x4)0.f;

  for (int s = 0; s < NS; s++){
    bf16x8 wf[JW];
#pragma unroll
    for (int j = 0; j < JW; j++)
      wf[j] = *(const bf16x8*)(Wc + ((w + 4*j)*16 + c16)*IC + s*32 + g*8);
#pragma unroll
    for (int mt = 0; mt < 5; mt++){
      bf16x8 af = *(const bf16x8*)(smem + ((s*5 + mt)*4 + g)*128 + pi16(c16, mt)*8);
#pragma unroll
      for (int j = 0; j < JW; j++)
        acc[mt][j] = __builtin_amdgcn_mfma_f32_16x16x32_bf16(af, wf[j], acc[mt][j], 0,0,0);
    }
  }

  float* dl = (float*)smem;
#pragma unroll
  for (int ph = 0; ph < PHASES; ph++){
    __syncthreads();
    float st_s[2], st_ss[2];
#pragma unroll
    for (int jj = 0; jj < 2; jj++){
      int j = ph*2 + jj;
      int ct = w + 4*j;
      int rl = (ct & 7)*16 + c16;
      float bb = bias[ct*16 + c16];
      float s = 0.f, ss = 0.f;
#pragma unroll
      for (int mt = 0; mt < 5; mt++){
        f32x4 v = acc[mt][j];
        float4 vv;
        vv.x = v[0]+bb; vv.y = v[1]+bb; vv.z = v[2]+bb; vv.w = v[3]+bb;
        *(float4*)&dl[rl*84 + mt*16 + 4*g] = vv;
        s  += vv.x + vv.y + vv.z + vv.w;
        ss += vv.x*vv.x + vv.y*vv.y + vv.z*vv.z + vv.w*vv.w;
      }
      st_s[jj] = s; st_ss[jj] = ss;
    }
    if (STATS && ph == SPH){
#pragma unroll
      for (int jj = 0; jj < 2; jj++){
        float s = st_s[jj], ss = st_ss[jj];
        s += __shfl_xor(s, 16); ss += __shfl_xor(ss, 16);
        s += __shfl_xor(s, 32); ss += __shfl_xor(ss, 32);
        if (g == 0){
          int ct = w + 4*(ph*2 + jj);
          int rl = (ct & 7)*16 + c16;
          int off = (b*NTIL + bx)*128 + rl;
          pstat[off]           = s;
          pstat[PSTRIDE + off] = ss;
        }
      }
    }
    __syncthreads();
    float* dst = ph ? out1 : out0;
#pragma unroll
    for (int kk = 0; kk < 10; kk++){
      int idx = kk*256 + tid;
      int r = idx/20, c4 = idx - 20*r;
      *(float4*)(dst + ((size_t)(b*128 + r))*NPTS + n0 + 4*c4) = *(float4*)&dl[r*84 + 4*c4];
    }
  }
}

// ---- reduce pstat -> per-(b,c) m and combined inorm(1e-5)+bnorm scale (parallel) ----
__global__ __launch_bounds__(1024) void k_red(const float* __restrict__ pstat,
                                              float* __restrict__ cm, float* __restrict__ cs){
  __shared__ float msh[2048], vsh[2048], wsh[2048];
  int t = threadIdx.x;
#pragma unroll
  for (int h = 0; h < 2; h++){
    int p = t + h*1024;
    int b = p >> 7, c = p & 127;
    float s = 0.f, ss = 0.f;
    for (int tt = 0; tt < NTIL; tt++){
      int off = (b*NTIL + tt)*128 + c;
      s  += pstat[off];
      ss += pstat[PSTRIDE + off];
    }
    float m = s * (1.f/(float)NPTS);
    float v = ss * (1.f/(float)NPTS) - m*m;
    msh[p] = m; vsh[p] = v; wsh[p] = v/(v + 1e-5f);
  }
  __syncthreads();
  if (t < 128){
    float V = 0.f;
    for (int b = 0; b < NB; b++) V += wsh[b*128 + t];
    float bs = rsqrtf(V*(1.f/(float)NB) + 1e-5f);
    for (int b = 0; b < NB; b++){
      cm[b*COx + t] = msh[b*128 + t];
      cs[b*COx + t] = rsqrtf(vsh[b*128 + t] + 1e-5f) * bs;
    }
  }
}

// o3 = relu(norm(c3)+x1); t = x_row + g*o3; out = 0.5*(t + mean_c t)
__global__ __launch_bounds__(256) void k_final(const float* __restrict__ c3, const float* __restrict__ x1,
    const float* __restrict__ x_row, const float* __restrict__ cm, const float* __restrict__ cs,
    const float* __restrict__ gamma1, float* __restrict__ out)
{
  const int b  = blockIdx.y;
  const int n0 = blockIdx.x * 50;
  const int tid = threadIdx.x;
  const float g = gamma1[0];
  __shared__ float tt[128][50];
  __shared__ float part[4][50];
  for (int idx = tid; idx < 128*50; idx += 256){
    int c = idx / 50; int j = idx - c*50;
    size_t off = ((size_t)b*COx + c)*NPTS + n0 + j;
    float o3 = fmaxf((c3[off] - cm[b*COx + c]) * cs[b*COx + c] + x1[off], 0.f);
    tt[c][j] = x_row[off] + g * o3;
  }
  __syncthreads();
  if (tid < 200){
    int gg = tid / 50, j = tid - gg*50;
    float s = 0.f;
    for (int c = gg*32; c < gg*32 + 32; c++) s += tt[c][j];
    part[gg][j] = s;
  }
  __syncthreads();
  for (int idx = tid; idx < 128*50; idx += 256){
    int c = idx / 50; int j = idx - c*50;
    float mean = (part[0][j] + part[1][j] + part[2][j] + part[3][j]) * (1.f/128.f);
    out[((size_t)b*COx + c)*NPTS + n0 + j] = 0.5f * (tt[c][j] + mean);
  }
}

extern "C" void kernel_launch(void* const* d_in, const int* in_sizes, int n_in,
                              void* d_out, int out_size, void* d_ws, size_t ws_size,
                              hipStream_t stream){
  (void)in_sizes; (void)n_in; (void)out_size; (void)ws_size;
  const float* x_row   = (const float*)d_in[0];
  const float* x_local = (const float*)d_in[1];
  const float* w_att1  = (const float*)d_in[2];
  const float* b_att1  = (const float*)d_in[3];
  const float* wq      = (const float*)d_in[4];
  const float* bq      = (const float*)d_in[5];
  const float* wk      = (const float*)d_in[6];
  const float* bk      = (const float*)d_in[7];
  const float* wv      = (const float*)d_in[8];
  const float* bv      = (const float*)d_in[9];
  const float* w_right = (const float*)d_in[10];
  const float* b_right = (const float*)d_in[11];
  const float* w_l1    = (const float*)d_in[12];
  const float* b_l1    = (const float*)d_in[13];
  const float* w_l2    = (const float*)d_in[14];
  const float* b_l2    = (const float*)d_in[15];
  const float* w_l3    = (const float*)d_in[16];
  const float* b_l3    = (const float*)d_in[17];
  const float* gamma1  = (const float*)d_in[18];
  float* out = (float*)d_out;

  float*  ws     = (float*)d_ws;
  float*  sum    = ws;                        // 4096
  float*  sumsq  = ws + 4096;                 // 4096
  float*  mArr   = ws + 8192;                 // 4096
  float*  sArr   = ws + 12288;                // 4096
  ushort* Wf     = (ushort*)(ws + 16384);     // 65536 us = 32768 floats
  float*  bKV    = ws + 49152;                // 256
  ushort* Wq     = (ushort*)(ws + 49408);     // 16384 us
  ushort* W2     = (ushort*)(ws + 57600);     // 65536 us
  ushort* W3     = (ushort*)(ws + 90368);     // 16384 us
  ushort* W4     = (ushort*)(ws + 98560);     // 16384 us
  float*  bias2  = ws + 106752;               // 256
  float*  cm     = ws + 107008;               // 2048
  float*  cs     = ws + 109056;               // 2048
  float*  pstat  = ws + 111104;               // 102400 (s plane + ss plane)
  float*  P0 = ws + 262144;                   // 4,096,000 each
  float*  P1 = P0 + 4096000;
  float*  P2 = P1 + 4096000;
  float*  P3 = P2 + 4096000;

  // stats + weight prep
  k_xstats <<<4096, 256, 0, stream>>>(x_local, sum, sumsq);
  k_xscale <<<1, 256, 0, stream>>>(sum, sumsq, mArr, sArr);
  k_prep_kv<<<256, 256, 0, stream>>>(w_att1, wk, wv, b_att1, bk, bv, Wf, bKV);
  k_prepW  <<<450, 256, 0, stream>>>(wq, w_right, w_l1, w_l2, w_l3, b_right, b_l1,
                                     Wq, W2, W3, W4, bias2);

  // fused MFMA attention (q computed in-kernel) -> out_local (P0)
  k_attn_mfma<<<dim3(250, NB), 256, 0, stream>>>(x_local, x_row, mArr, sArr, Wf, bKV, Wq, bq, P0);

  // x1 (P1), c1 (P2) + stats(c1)
  k_mconv<1><<<dim3(NTIL, NB), 256, 0, stream>>>(x_row, P0, W2, bias2,
                                                 nullptr, nullptr, P1, P2, nullptr, pstat);
  k_red<<<1, 1024, 0, stream>>>(pstat, cm, cs);

  // stage o1 = relu(norm(c1))+x1; c2 (P3); u = o1+x1 -> P0; stats(c2)
  k_mconv<2><<<dim3(NTIL, NB), 256, 0, stream>>>(P2, P1, W3, b_l2,
                                                 cm, cs, P3, nullptr, P0, pstat);
  k_red<<<1, 1024, 0, stream>>>(pstat, cm, cs);

  // stage o2 = relu(norm(c2))+u; c3 (P2); stats(c3)
  k_mconv<3><<<dim3(NTIL, NB), 256, 0, stream>>>(P3, P0, W4, b_l3,
                                                 cm, cs, P2, nullptr, nullptr, pstat);
  k_red<<<1, 1024, 0, stream>>>(pstat, cm, cs);

  // final
  k_final<<<dim3(NPTS/50, NB), 256, 0, stream>>>(P2, P1, x_row, cm, cs, gamma1, out);
}